// Round 16
// baseline (1029.225 us; speedup 1.0000x reference)
//
#include <hip/hip_runtime.h>
#include <hip/hip_bf16.h>

// ---------------------------------------------------------------------------
// SHINE forward, full bf16-MFMA version with hi/lo-split activations+weights.
// Workspace (222,445,568 B total, unchanged layout):
//   concat : bf16 NHWC [2][65536][576]          150,994,944 B
//   Xhi,Xlo,Yhi,Ylo : bf16 NHWC [2][65536][64]  4 x 16,777,216 B
//   packs  : conv B-frags (hi,lo)                 3,604,480 B
//   w1p    : head W1 frags                          663,552 B
//   w2p    : head W2 frags                           73,728 B
// R16: out1_gemm v4 = weight-stream amortization: 512-thread blocks, 128 px
//      (2 px-groups x mt-split {5,5,4,4}), same 36.9KB stage now shared by
//      2x pixels -> per-px weight traffic halved, total L2 weight stream
//      halved. acc[4][5]=80 VGPR kept (no R14 occupancy cliff). Epilogue =
//      proven stride-300 transpose, run per px-half. Bit-identical math.
// ---------------------------------------------------------------------------

#define HPX 65536   // 256*256
#define FCH 64
#define CHPX 32768  // head px-chunk

typedef __attribute__((ext_vector_type(8))) short  short8;
typedef __attribute__((ext_vector_type(4))) float  floatx4;

__device__ __forceinline__ float gelu_f(float x) {
  return 0.5f * x * (1.0f + erff(x * 0.70710678118654752440f));
}
__device__ __forceinline__ unsigned short f2bf(float x) {  // RNE
  unsigned u = __float_as_uint(x);
  unsigned r = (u + 0x7FFFu + ((u >> 16) & 1u)) >> 16;
  return (unsigned short)r;
}
__device__ __forceinline__ float bf2f(unsigned short h) {
  return __uint_as_float(((unsigned)h) << 16);
}

// ---------------- conv0 part A: channels 0..47 = gelu(w0b[c] * target)
__global__ __launch_bounds__(256) void conv0_elem_kernel(
    const float* __restrict__ img,   // [2][5][256][256]
    const float* __restrict__ w0b,   // [48]
    unsigned short* __restrict__ ohi,  // [2][65536][64]
    unsigned short* __restrict__ olo)
{
  int t = blockIdx.x * 256 + threadIdx.x;     // over 2*HPX*6 = 786432
  int cg = t % 6;
  int pn = t / 6;                              // n*HPX + px
  int px = pn & (HPX - 1);
  int n  = pn >> 16;
  float x = img[(long)n * 5 * HPX + 2 * HPX + px];
  short8 oh, ol;
  #pragma unroll
  for (int j = 0; j < 8; j++) {
    int c = cg * 8 + j;
    float v = gelu_f(w0b[c] * x);
    unsigned short hb = f2bf(v);
    oh[j] = (short)hb;
    ol[j] = (short)f2bf(v - bf2f(hb));
  }
  long o = ((long)pn) * 64 + cg * 8;
  *(short8*)&ohi[o] = oh;
  *(short8*)&olo[o] = ol;
}

// ---------------- conv0 part B: channels 48..63 = gelu(3x3 conv over 4 feats)
__global__ __launch_bounds__(256) void conv0_conv_kernel(
    const float* __restrict__ img,   // [2][5][256][256]
    const float* __restrict__ w0a,   // [16][4][3][3]
    unsigned short* __restrict__ ohi,
    unsigned short* __restrict__ olo)
{
  int t = blockIdx.x * 256 + threadIdx.x;     // over 2*HPX*2 = 262144
  int cg = t & 1;
  int pn = t >> 1;
  int px = pn & (HPX - 1);
  int n  = pn >> 16;
  int y = px >> 8, x = px & 255;
  const float* im = img + (long)n * 5 * HPX;
  const int map4[4] = {0, 1, 3, 4};
  float vreg[36];
  #pragma unroll
  for (int fi = 0; fi < 4; fi++)
    #pragma unroll
    for (int ky = 0; ky < 3; ky++)
      #pragma unroll
      for (int kx = 0; kx < 3; kx++) {
        int yy = y + ky - 1, xx = x + kx - 1;
        bool ok = ((unsigned)yy < 256u) && ((unsigned)xx < 256u);
        vreg[(fi * 3 + ky) * 3 + kx] =
            ok ? im[(long)map4[fi] * HPX + yy * 256 + xx] : 0.0f;
      }
  short8 oh, ol;
  #pragma unroll
  for (int j = 0; j < 8; j++) {
    int co = cg * 8 + j;                       // 0..15 -> output ch 48+co
    const float* wr = w0a + co * 36;
    float r = 0.0f;
    #pragma unroll
    for (int q = 0; q < 36; q++) r = fmaf(wr[q], vreg[q], r);
    float v = gelu_f(r);
    unsigned short hb = f2bf(v);
    oh[j] = (short)hb;
    ol[j] = (short)f2bf(v - bf2f(hb));
  }
  long o = ((long)pn) * 64 + 48 + cg * 8;
  *(short8*)&ohi[o] = oh;
  *(short8*)&olo[o] = ol;
}

// ---------------- batched conv-weight packing into MFMA B-frags (hi,lo)
struct JobArr { int4 j[29]; };   // {src_sel, src_off, ntaps, dst_off}

__global__ __launch_bounds__(256) void pack_conv_kernel(
    const float* __restrict__ cl10, const float* __restrict__ cl2,
    const float* __restrict__ first_p, const float* __restrict__ dilres_p,
    const float* __restrict__ dil_p, const float* __restrict__ ups_w,
    unsigned short* __restrict__ packs, JobArr jobs)
{
  int4 jb = jobs.j[blockIdx.y];
  int ntaps = jb.z;
  int idx = blockIdx.x * 256 + threadIdx.x;
  if (idx >= ntaps * 8192) return;
  int j  = idx & 7;
  int l  = (idx >> 3) & 63;
  int s  = (idx >> 9) & 1;
  int nt = (idx >> 10) & 3;
  int kt = (idx >> 12) & 1;
  int tap = idx >> 13;
  int oc = nt * 16 + (l & 15);
  int ci = kt * 32 + (l >> 4) * 8 + j;
  const float* src;
  switch (jb.x) {
    case 0: src = cl10; break;
    case 1: src = cl2; break;
    case 2: src = first_p; break;
    case 3: src = dilres_p; break;
    case 4: src = dil_p; break;
    default: src = ups_w; break;
  }
  float w = src[jb.y + (oc * 64 + ci) * ntaps + tap];
  unsigned short hi = f2bf(w);
  unsigned short v = (s == 0) ? hi : f2bf(w - bf2f(hi));
  packs[jb.w + idx] = v;
}

// ---------------- head weight packing (hi+lo)
__global__ __launch_bounds__(256) void pack_w1_kernel(
    const float* __restrict__ w1, unsigned short* __restrict__ w1p)
{
  int t = blockIdx.x * 256 + threadIdx.x;      // 18*18*512
  if (t >= 18 * 18 * 512) return;
  int j = t & 7, l = (t >> 3) & 63;
  int mt = (t >> 9) % 18, kt = (t >> 9) / 18;
  int oc = mt * 16 + (l & 15);
  int k  = kt * 32 + (l >> 4) * 8 + j;
  float w = w1[oc * 576 + k];
  unsigned short hi = f2bf(w);
  unsigned short lo = f2bf(w - bf2f(hi));
  long base = ((long)(kt * 18 + mt) * 2) * 512 + l * 8 + j;
  w1p[base] = hi;
  w1p[base + 512] = lo;
}
__global__ __launch_bounds__(256) void pack_w2_kernel(
    const float* __restrict__ w2, unsigned short* __restrict__ w2p)
{
  int t = blockIdx.x * 256 + threadIdx.x;      // 9*4*512
  if (t >= 9 * 4 * 512) return;
  int j = t & 7, l = (t >> 3) & 63;
  int ot = (t >> 9) % 4, kt = (t >> 9) / 4;
  int oc = ot * 16 + (l & 15);
  int k  = kt * 32 + (l >> 4) * 8 + j;
  float w = w2[oc * 288 + k];
  unsigned short hi = f2bf(w);
  unsigned short lo = f2bf(w - bf2f(hi));
  long base = ((long)(kt * 4 + ot) * 2) * 512 + l * 8 + j;
  w2p[base] = hi;
  w2p[base + 512] = lo;
}

// ---------------- software-pipelined MFMA conv (implicit GEMM, 16x16x32 bf16)
template <int NTAPS, int MT, bool RESID, bool TO_CONCAT>
__global__ __launch_bounds__(256) void conv_pipe_kernel(
    const unsigned short* __restrict__ in_hi,   // NHWC [n][npx_in][64]
    const unsigned short* __restrict__ in_lo,
    const unsigned short* __restrict__ wp,      // packed frags
    const unsigned short* __restrict__ res_hi,
    const unsigned short* __restrict__ res_lo,
    unsigned short* __restrict__ out_hi,        // act hi or concat
    unsigned short* __restrict__ out_lo,
    int Hs, int logW, int dil, int ccol)
{
  __shared__ short8 wst[2][1024];               // 2 x 16 KB double buffer
  __shared__ float  ftb[4][16][65];             // per-wave f32 transpose tiles
  const int tid  = threadIdx.x;
  const int lane = tid & 63;
  const int wave = tid >> 6;
  const int row  = lane & 15;
  const int g    = lane >> 4;
  const int n    = blockIdx.z;
  const int Ws   = 1 << logW;
  const int npx_in = Hs << logW;
  const int opx0 = blockIdx.x * (64 * MT) + wave * (16 * MT);

  const unsigned short* ihi = in_hi + (long)n * npx_in * 64;
  const unsigned short* ilo = in_lo + (long)n * npx_in * 64;
  const short8* wpv = (const short8*)wp;

  int ry[MT], rx[MT];
  #pragma unroll
  for (int mt = 0; mt < MT; mt++) {
    int p = opx0 + mt * 16 + row;
    ry[mt] = p >> logW;
    rx[mt] = p & (Ws - 1);
  }

  floatx4 acc[MT][4];
  #pragma unroll
  for (int mt = 0; mt < MT; mt++)
    #pragma unroll
    for (int nt = 0; nt < 4; nt++) acc[mt][nt] = (floatx4){0.f, 0.f, 0.f, 0.f};

  const short8 zz = {0, 0, 0, 0, 0, 0, 0, 0};
  short8 sreg[4];
  short8 ahA[MT][2], alA[MT][2], ahB[MT][2], alB[MT][2];

  auto stage_issue = [&](int t) {
    #pragma unroll
    for (int p = 0; p < 4; p++)
      sreg[p] = wpv[(long)t * 1024 + tid + p * 256];
  };
  auto stage_write = [&](int b) {
    #pragma unroll
    for (int p = 0; p < 4; p++)
      wst[b][tid + p * 256] = sreg[p];
  };
  auto a_load = [&](short8 (&ah)[MT][2], short8 (&al)[MT][2], int t) {
    const int kk  = (NTAPS == 9) ? t : (t < 4 ? t : t + 1);
    const int dyd = (kk / 3 - 1) * dil, dxd = (kk % 3 - 1) * dil;
    #pragma unroll
    for (int mt = 0; mt < MT; mt++) {
      int yy = ry[mt] + dyd, xx = rx[mt] + dxd;
      bool ok = ((unsigned)yy < (unsigned)Hs) && ((unsigned)xx < (unsigned)Ws);
      long base = ok ? (long)((yy << logW) + xx) * 64 : 0;
      #pragma unroll
      for (int kt = 0; kt < 2; kt++) {
        long a = base + kt * 32 + g * 8;
        short8 h = *(const short8*)(ihi + a);
        short8 l = *(const short8*)(ilo + a);
        ah[mt][kt] = ok ? h : zz;
        al[mt][kt] = ok ? l : zz;
      }
    }
  };
  auto compute = [&](int b, short8 (&ah)[MT][2], short8 (&al)[MT][2]) {
    #pragma unroll
    for (int kt = 0; kt < 2; kt++)
      #pragma unroll
      for (int nt = 0; nt < 4; nt++) {
        short8 bh = wst[b][(kt * 4 + nt) * 128 + lane];
        short8 bl = wst[b][(kt * 4 + nt) * 128 + 64 + lane];
        #pragma unroll
        for (int mt = 0; mt < MT; mt++) {
          acc[mt][nt] = __builtin_amdgcn_mfma_f32_16x16x32_bf16(ah[mt][kt], bh, acc[mt][nt], 0, 0, 0);
          acc[mt][nt] = __builtin_amdgcn_mfma_f32_16x16x32_bf16(ah[mt][kt], bl, acc[mt][nt], 0, 0, 0);
          acc[mt][nt] = __builtin_amdgcn_mfma_f32_16x16x32_bf16(al[mt][kt], bh, acc[mt][nt], 0, 0, 0);
        }
      }
  };

  // prologue: stage + A for tap 0
  stage_issue(0);
  a_load(ahA, alA, 0);
  stage_write(0);
  __syncthreads();

  #pragma unroll
  for (int tt = 0; tt < NTAPS; tt++) {
    const int b = tt & 1;
    if (tt + 1 < NTAPS) {
      stage_issue(tt + 1);                       // global loads, early
      if ((tt & 1) == 0) a_load(ahB, alB, tt + 1);
      else               a_load(ahA, alA, tt + 1);
    }
    if ((tt & 1) == 0) compute(b, ahA, alA);     // hides the loads above
    else               compute(b, ahB, alB);
    if (tt + 1 < NTAPS) {
      stage_write(b ^ 1);                        // write-late into other buf
      __syncthreads();                           // ONE barrier per tap
    }
  }

  // epilogue: acc -> f32 LDS tile -> (+coalesced resid) -> gelu -> short8 out
  #pragma unroll
  for (int mt = 0; mt < MT; mt++) {
    __builtin_amdgcn_wave_barrier();
    #pragma unroll
    for (int nt = 0; nt < 4; nt++)
      #pragma unroll
      for (int r = 0; r < 4; r++)
        ftb[wave][g * 4 + r][nt * 16 + row] = acc[mt][nt][r];
    __builtin_amdgcn_wave_barrier();
    const int pxb = opx0 + mt * 16;
    const int pxl = lane >> 2;
    #pragma unroll
    for (int it = 0; it < 2; it++) {
      const int ch = (lane & 3) + it * 4;
      float vv[8];
      #pragma unroll
      for (int j = 0; j < 8; j++) vv[j] = ftb[wave][pxl][ch * 8 + j];
      if (RESID) {
        long rb = ((long)n * npx_in + pxb + pxl) * 64 + ch * 8;
        short8 rh = *(const short8*)(res_hi + rb);
        short8 rl = *(const short8*)(res_lo + rb);
        #pragma unroll
        for (int j = 0; j < 8; j++)
          vv[j] += bf2f((unsigned short)rh[j]) + bf2f((unsigned short)rl[j]);
      }
      short8 oh8, ol8;
      #pragma unroll
      for (int j = 0; j < 8; j++) {
        float v = gelu_f(vv[j]);
        unsigned short hb = f2bf(v);
        oh8[j] = (short)hb;
        ol8[j] = (short)f2bf(v - bf2f(hb));
      }
      if (TO_CONCAT) {
        *(short8*)&out_hi[((long)n * HPX + pxb + pxl) * 576 + ccol + ch * 8] = oh8;
      } else {
        *(short8*)&out_hi[((long)n * npx_in + pxb + pxl) * 64 + ch * 8] = oh8;
        *(short8*)&out_lo[((long)n * npx_in + pxb + pxl) * 64 + ch * 8] = ol8;
      }
    }
  }
}

// ---------------- bilinear-upsample 1x1 conv -> concat (coalesced epilogue)
template <int MT>
__global__ __launch_bounds__(256) void ups_mfma_kernel(
    const unsigned short* __restrict__ in_hi,   // NHWC [n][npx_in][64]
    const unsigned short* __restrict__ in_lo,
    const unsigned short* __restrict__ wp,      // packed frags (1 tap)
    unsigned short* __restrict__ outc,          // concat
    int Hs, int logW, int ccol)
{
  __shared__ short8 wst[1024];                  // 16 KB: one tap's 16 frags
  __shared__ unsigned short tb[4][16][76];
  const int tid  = threadIdx.x;
  const int lane = threadIdx.x & 63;
  const int wave = threadIdx.x >> 6;
  const int row  = lane & 15;
  const int g    = lane >> 4;
  const int n    = blockIdx.z;
  const int npx_in = Hs << logW;
  const int opx0 = blockIdx.x * (64 * MT) + wave * (16 * MT);

  const unsigned short* ihi = in_hi + (long)n * npx_in * 64;
  const unsigned short* ilo = in_lo + (long)n * npx_in * 64;
  const short8* wpv = (const short8*)wp;

  int b00[MT], b01[MT], b10[MT], b11[MT];
  float bwx[MT], bwy[MT];
  #pragma unroll
  for (int mt = 0; mt < MT; mt++) {
    int p = opx0 + mt * 16 + row;
    int Y = p >> 8, X = p & 255;
    float sc = (float)Hs * (1.0f / 256.0f);
    float fy = ((float)Y + 0.5f) * sc - 0.5f;
    float fx = ((float)X + 0.5f) * sc - 0.5f;
    int y0 = (int)floorf(fy), x0 = (int)floorf(fx);
    bwy[mt] = fy - (float)y0; bwx[mt] = fx - (float)x0;
    int y0c = min(max(y0, 0), Hs - 1), y1c = min(max(y0 + 1, 0), Hs - 1);
    int x0c = min(max(x0, 0), Hs - 1), x1c = min(max(x0 + 1, 0), Hs - 1);
    b00[mt] = (y0c * Hs + x0c) * 64; b01[mt] = (y0c * Hs + x1c) * 64;
    b10[mt] = (y1c * Hs + x0c) * 64; b11[mt] = (y1c * Hs + x1c) * 64;
  }

  floatx4 acc[MT][4];
  #pragma unroll
  for (int mt = 0; mt < MT; mt++)
    #pragma unroll
    for (int nt = 0; nt < 4; nt++) acc[mt][nt] = (floatx4){0.f, 0.f, 0.f, 0.f};

  #pragma unroll
  for (int p = 0; p < 4; p++)
    wst[tid + p * 256] = wpv[tid + p * 256];
  __syncthreads();

  #pragma unroll
  for (int kt = 0; kt < 2; kt++) {
    const int ko = kt * 32 + g * 8;
    short8 ah[MT], al[MT];
    #pragma unroll
    for (int mt = 0; mt < MT; mt++) {
      short8 h00 = *(const short8*)(ihi + b00[mt] + ko);
      short8 l00 = *(const short8*)(ilo + b00[mt] + ko);
      short8 h01 = *(const short8*)(ihi + b01[mt] + ko);
      short8 l01 = *(const short8*)(ilo + b01[mt] + ko);
      short8 h10 = *(const short8*)(ihi + b10[mt] + ko);
      short8 l10 = *(const short8*)(ilo + b10[mt] + ko);
      short8 h11 = *(const short8*)(ihi + b11[mt] + ko);
      short8 l11 = *(const short8*)(ilo + b11[mt] + ko);
      short8 hh, ll;
      #pragma unroll
      for (int j = 0; j < 8; j++) {
        float v00 = bf2f((unsigned short)h00[j]) + bf2f((unsigned short)l00[j]);
        float v01 = bf2f((unsigned short)h01[j]) + bf2f((unsigned short)l01[j]);
        float v10 = bf2f((unsigned short)h10[j]) + bf2f((unsigned short)l10[j]);
        float v11 = bf2f((unsigned short)h11[j]) + bf2f((unsigned short)l11[j]);
        float v0 = v00 + bwx[mt] * (v01 - v00);
        float v1 = v10 + bwx[mt] * (v11 - v10);
        float v  = v0 + bwy[mt] * (v1 - v0);
        unsigned short hb = f2bf(v);
        hh[j] = (short)hb;
        ll[j] = (short)f2bf(v - bf2f(hb));
      }
      ah[mt] = hh; al[mt] = ll;
    }
    #pragma unroll
    for (int nt = 0; nt < 4; nt++) {
      short8 bh = wst[(kt * 4 + nt) * 2 * 64 + lane];
      short8 bl = wst[((kt * 4 + nt) * 2 + 1) * 64 + lane];
      #pragma unroll
      for (int mt = 0; mt < MT; mt++) {
        acc[mt][nt] = __builtin_amdgcn_mfma_f32_16x16x32_bf16(ah[mt], bh, acc[mt][nt], 0, 0, 0);
        acc[mt][nt] = __builtin_amdgcn_mfma_f32_16x16x32_bf16(ah[mt], bl, acc[mt][nt], 0, 0, 0);
        acc[mt][nt] = __builtin_amdgcn_mfma_f32_16x16x32_bf16(al[mt], bh, acc[mt][nt], 0, 0, 0);
      }
    }
  }

  #pragma unroll
  for (int mt = 0; mt < MT; mt++) {
    __builtin_amdgcn_wave_barrier();
    #pragma unroll
    for (int nt = 0; nt < 4; nt++)
      #pragma unroll
      for (int r = 0; r < 4; r++)
        tb[wave][g * 4 + r][nt * 16 + row] = f2bf(gelu_f(acc[mt][nt][r]));
    __builtin_amdgcn_wave_barrier();
    const int pxb = opx0 + mt * 16;
    const int pxl = lane >> 2;
    #pragma unroll
    for (int it = 0; it < 2; it++) {
      int ch = (lane & 3) + it * 4;
      short8 v8 = *(const short8*)&tb[wave][pxl][ch * 8];
      *(short8*)&outc[((long)n * HPX + pxb + pxl) * 576 + ccol + ch * 8] = v8;
    }
  }
}

// ---------------- 2x2 average pool, NHWC hi/lo -> NHWC hi/lo
__global__ __launch_bounds__(256) void avgpool_nhwc_kernel(
    const unsigned short* __restrict__ ihi, const unsigned short* __restrict__ ilo,
    unsigned short* __restrict__ ohi, unsigned short* __restrict__ olo,
    int logWo)
{
  const int lognpo = 2 * logWo;
  long t = (long)blockIdx.x * 256 + threadIdx.x;   // over 2*npo*8
  int cg = (int)(t & 7);
  int p  = (int)((t >> 3) & ((1 << lognpo) - 1));
  int n  = (int)(t >> (3 + lognpo));
  int y = p >> logWo, x = p & ((1 << logWo) - 1);
  int Wi = 2 << logWo;
  long ib = ((long)n * (4 << lognpo) + (long)(2 * y) * Wi + 2 * x) * 64 + cg * 8;
  short8 h00 = *(const short8*)(ihi + ib);
  short8 h01 = *(const short8*)(ihi + ib + 64);
  short8 h10 = *(const short8*)(ihi + ib + (long)Wi * 64);
  short8 h11 = *(const short8*)(ihi + ib + (long)Wi * 64 + 64);
  short8 l00 = *(const short8*)(ilo + ib);
  short8 l01 = *(const short8*)(ilo + ib + 64);
  short8 l10 = *(const short8*)(ilo + ib + (long)Wi * 64);
  short8 l11 = *(const short8*)(ilo + ib + (long)Wi * 64 + 64);
  short8 oh, ol;
  #pragma unroll
  for (int j = 0; j < 8; j++) {
    float v = 0.25f * ((bf2f((unsigned short)h00[j]) + bf2f((unsigned short)l00[j])) +
                       (bf2f((unsigned short)h01[j]) + bf2f((unsigned short)l01[j])) +
                       (bf2f((unsigned short)h10[j]) + bf2f((unsigned short)l10[j])) +
                       (bf2f((unsigned short)h11[j]) + bf2f((unsigned short)l11[j])));
    unsigned short hb = f2bf(v);
    oh[j] = (short)hb;
    ol[j] = (short)f2bf(v - bf2f(hb));
  }
  long ob = (((long)n << lognpo) + p) * 64 + cg * 8;
  *(short8*)(ohi + ob) = oh;
  *(short8*)(olo + ob) = ol;
}

// ---------------- head stage 1 GEMM v4: h = gelu(W1 @ concat), one px-chunk
// 512 threads, 128 px/block: 8 waves = 2 px-groups x mt-split {5,5,4,4}.
// Single 36.9KB stage buffer shared by 2x pixels (per-px weight traffic
// halved); register-prefetch of kt+1 weights before compute(kt). Epilogue =
// stride-300 transpose run per px-half. Math order identical (same absmax).
__global__ __launch_bounds__(512) void out1_gemm_kernel(
    const unsigned short* __restrict__ v,       // concat NHWC [2][65536][576]
    const unsigned short* __restrict__ w1p,
    unsigned short* __restrict__ h,             // [2][CHPX][288] bf16
    int cpx)
{
  __shared__ short8 ws8[2400];                  // 38,400 B (stage / transpose)
  const int tid  = threadIdx.x;
  const int lane = tid & 63;
  const int wave = tid >> 6;                    // 0..7
  const int row  = lane & 15;
  const int g    = lane >> 4;
  const int n    = blockIdx.y;
  const int px0  = cpx + blockIdx.x * 128;      // block covers 128 px
  const int pgrp = wave >> 2;                   // 0: px 0..63, 1: px 64..127
  const int w4   = wave & 3;
  const int mtb  = (w4 < 2) ? w4 * 5 : 10 + (w4 - 2) * 4;
  const int MTN  = (w4 < 2) ? 5 : 4;
  const short8* w1v = (const short8*)w1p;
  const unsigned short* vb = v + ((long)n * HPX + px0 + pgrp * 64) * 576;

  floatx4 acc[4][5];
  #pragma unroll
  for (int t = 0; t < 4; t++)
    #pragma unroll
    for (int m = 0; m < 5; m++) acc[t][m] = (floatx4){0.f, 0.f, 0.f, 0.f};

  short8 sreg[5];
  auto stage_issue = [&](int kt) {
    #pragma unroll
    for (int p = 0; p < 4; p++)
      sreg[p] = w1v[kt * 2304 + tid + p * 512];
    if (tid < 256) sreg[4] = w1v[kt * 2304 + 2048 + tid];
  };
  auto stage_write = [&]() {
    #pragma unroll
    for (int p = 0; p < 4; p++)
      ws8[tid + p * 512] = sreg[p];
    if (tid < 256) ws8[2048 + tid] = sreg[4];
  };

  // prologue: stage kt 0
  stage_issue(0);
  stage_write();
  __syncthreads();

  for (int kt = 0; kt < 18; kt++) {
    if (kt + 1 < 18) stage_issue(kt + 1);        // global loads, early

    short8 a[4];
    #pragma unroll
    for (int t = 0; t < 4; t++)
      a[t] = *(const short8*)(vb + (long)(t * 16 + row) * 576 + kt * 32 + g * 8);
    #pragma unroll
    for (int m = 0; m < 5; m++) {
      if (m < MTN) {
        short8 bh = ws8[((mtb + m) * 2 + 0) * 64 + lane];
        short8 bl = ws8[((mtb + m) * 2 + 1) * 64 + lane];
        #pragma unroll
        for (int t = 0; t < 4; t++) {
          acc[t][m] = __builtin_amdgcn_mfma_f32_16x16x32_bf16(a[t], bh, acc[t][m], 0, 0, 0);
          acc[t][m] = __builtin_amdgcn_mfma_f32_16x16x32_bf16(a[t], bl, acc[t][m], 0, 0, 0);
        }
      }
    }
    if (kt + 1 < 18) {
      __syncthreads();                           // all waves done reading ws8
      stage_write();                             // write-late from registers
      __syncthreads();                           // ws8 ready for kt+1
    }
  }

  // epilogue: per px-half, gelu -> bf16 -> LDS [64][300] -> coalesced writes
  __syncthreads();
  unsigned short* hs2 = (unsigned short*)ws8;
  #pragma unroll
  for (int half = 0; half < 2; half++) {
    if (pgrp == half) {
      #pragma unroll
      for (int m = 0; m < 5; m++) {
        if (m < MTN) {
          #pragma unroll
          for (int t = 0; t < 4; t++)
            #pragma unroll
            for (int r = 0; r < 4; r++)
              hs2[(t * 16 + g * 4 + r) * 300 + (mtb + m) * 16 + row] =
                  f2bf(gelu_f(acc[t][m][r]));
        }
      }
    }
    __syncthreads();
    #pragma unroll
    for (int p = 0; p < 5; p++) {
      int li = tid + p * 512;                    // 2304 chunks of 16B
      if (li < 2304) {
        int px = li / 36, c16 = li % 36;
        short8 v8 = *(const short8*)&hs2[px * 300 + c16 * 8];
        *(short8*)&h[((long)n * CHPX + (px0 - cpx) + half * 64 + px) * 288 +
                     c16 * 8] = v8;
      }
    }
    __syncthreads();
  }
}

// ---------------- head stage 2: out = w3 . gelu(W2 @ h), one px-chunk
__global__ __launch_bounds__(256) void out2_gemm_kernel(
    const unsigned short* __restrict__ h,       // [2][CHPX][288] bf16
    const unsigned short* __restrict__ w2p,
    const float* __restrict__ w3,               // [64]
    float* __restrict__ out,                    // [2][65536]
    int cpx)
{
  __shared__ short8 w2s[4608];                  // 73,728 B, whole w2p
  const int tid  = threadIdx.x;
  const int lane = tid & 63;
  const int wave = tid >> 6;
  const int row  = lane & 15;
  const int g    = lane >> 4;
  const int n    = blockIdx.y;
  const int pxc  = blockIdx.x * 256 + wave * 64; // px within chunk
  const short8* w2v = (const short8*)w2p;

  #pragma unroll
  for (int p = 0; p < 18; p++)
    w2s[tid + p * 256] = w2v[tid + p * 256];
  __syncthreads();

  floatx4 acc2[4][4];
  #pragma unroll
  for (int t = 0; t < 4; t++)
    #pragma unroll
    for (int ot = 0; ot < 4; ot++) acc2[t][ot] = (floatx4){0.f, 0.f, 0.f, 0.f};

  for (int kt = 0; kt < 9; kt++) {
    short8 a[4];
    #pragma unroll
    for (int t = 0; t < 4; t++)
      a[t] = *(const short8*)&h[((long)n * CHPX + pxc + t * 16 + row) * 288 +
                                kt * 32 + g * 8];
    #pragma unroll
    for (int ot = 0; ot < 4; ot++) {
      short8 bh = w2s[((kt * 4 + ot) * 2 + 0) * 64 + lane];
      short8 bl = w2s[((kt * 4 + ot) * 2 + 1) * 64 + lane];
      #pragma unroll
      for (int t = 0; t < 4; t++) {
        acc2[t][ot] = __builtin_amdgcn_mfma_f32_16x16x32_bf16(a[t], bh, acc2[t][ot], 0, 0, 0);
        acc2[t][ot] = __builtin_amdgcn_mfma_f32_16x16x32_bf16(a[t], bl, acc2[t][ot], 0, 0, 0);
      }
    }
  }

  float w3r[4];
  #pragma unroll
  for (int ot = 0; ot < 4; ot++) w3r[ot] = w3[ot * 16 + row];
  #pragma unroll
  for (int t = 0; t < 4; t++) {
    float r[4] = {0.f, 0.f, 0.f, 0.f};
    #pragma unroll
    for (int ot = 0; ot < 4; ot++)
      #pragma unroll
      for (int rr = 0; rr < 4; rr++)
        r[rr] = fmaf(w3r[ot], gelu_f(acc2[t][ot][rr]), r[rr]);
    #pragma unroll
    for (int rr = 0; rr < 4; rr++) {
      r[rr] += __shfl_xor(r[rr], 1);
      r[rr] += __shfl_xor(r[rr], 2);
      r[rr] += __shfl_xor(r[rr], 4);
      r[rr] += __shfl_xor(r[rr], 8);
    }
    if (row == 0) {
      int px = cpx + pxc + t * 16 + g * 4;
      #pragma unroll
      for (int rr = 0; rr < 4; rr++)
        out[(long)n * HPX + px + rr] = r[rr];
    }
  }
}

// ---------------------------------------------------------------------------
extern "C" void kernel_launch(void* const* d_in, const int* in_sizes, int n_in,
                              void* d_out, int out_size, void* d_ws, size_t ws_size,
                              hipStream_t stream) {
  const float* img      = (const float*)d_in[0];
  const float* w0a      = (const float*)d_in[1];
  const float* w0b      = (const float*)d_in[2];
  const float* first_p  = (const float*)d_in[3];
  const float* cl10     = (const float*)d_in[4];   // [4][2][64][64][9]
  const float* cl2      = (const float*)d_in[5];
  const float* dil_p    = (const float*)d_in[6];   // [4][64][64][8]
  const float* dilres_p = (const float*)d_in[7];
  const float* ups_w    = (const float*)d_in[8];   // [4][64][64]
  const float* w1       = (const float*)d_in[9];   // [288][576]
  const float* w2       = (const float*)d_in[10];  // [64][288]
  const float* w3       = (const float*)d_in[11];  // [64]

  const size_t CONCAT_B = 150994944ul;             // 2*65536*576*2
  const size_t ACT_B    = 16777216ul;              // 2*65536*64*2 per plane
  const size_t PACKS_B  = 3604480ul;               // 1,802,240 elems
  const size_t W1P_B    = 663552ul;
  const size_t W2P_B    = 73728ul;
  const size_t NEED = CONCAT_B + 4 * ACT_B + PACKS_B + W1P_B + W2P_B; // 222,445,568

  if (ws_size < NEED) {
    hipMemsetAsync(d_out, 0, (size_t)out_size * 4, stream);
    return;
  }

  char* wsb = (char*)d_ws;
  unsigned short* concat = (unsigned short*)wsb;
  unsigned short* Xhi = (unsigned short*)(wsb + CONCAT_B);
  unsigned short* Xlo = (unsigned short*)(wsb + CONCAT_B + ACT_B);
  unsigned short* Yhi = (unsigned short*)(wsb + CONCAT_B + 2 * ACT_B);
  unsigned short* Ylo = (unsigned short*)(wsb + CONCAT_B + 3 * ACT_B);
  unsigned short* packs = (unsigned short*)(wsb + CONCAT_B + 4 * ACT_B);
  unsigned short* w1p = (unsigned short*)(wsb + CONCAT_B + 4 * ACT_B + PACKS_B);
  unsigned short* w2p = (unsigned short*)(wsb + CONCAT_B + 4 * ACT_B + PACKS_B + W1P_B);
  unsigned short* hbuf = Xhi;   // head h buffer reuses dead act region

  // pack-destination offsets (elems)
  auto off_cl10   = [](int c) { return (long)c * 73728; };
  auto off_cl2    = [](int c) { return 589824l + (long)c * 73728; };
  const long OFF_FIRST = 1179648;
  auto off_dilres = [](int k) { return 1245184l + (long)k * 65536; };
  auto off_dil    = [](int k) { return 1507328l + (long)k * 65536; };
  auto off_ups    = [](int k) { return 1769472l + (long)k * 8192; };

  // ---- weight packing
  JobArr jobs;
  for (int c = 0; c < 8; c++) jobs.j[c]     = {0, c * 36864, 9, (int)off_cl10(c)};
  for (int c = 0; c < 8; c++) jobs.j[8 + c] = {1, c * 36864, 9, (int)off_cl2(c)};
  jobs.j[16] = {2, 0, 8, (int)OFF_FIRST};
  for (int k = 0; k < 4; k++) jobs.j[17 + k] = {3, k * 32768, 8, (int)off_dilres(k)};
  for (int k = 0; k < 4; k++) jobs.j[21 + k] = {4, k * 32768, 8, (int)off_dil(k)};
  for (int k = 0; k < 4; k++) jobs.j[25 + k] = {5, k * 4096, 1, (int)off_ups(k)};
  pack_conv_kernel<<<dim3(288, 29), 256, 0, stream>>>(
      cl10, cl2, first_p, dilres_p, dil_p, ups_w, packs, jobs);
  pack_w1_kernel<<<(18 * 18 * 512 + 255) / 256, 256, 0, stream>>>(w1, w1p);
  pack_w2_kernel<<<(9 * 4 * 512 + 255) / 256, 256, 0, stream>>>(w2, w2p);

  // ---- conv0 -> X @256 (elementwise part + 3x3 part)
  conv0_elem_kernel<<<(2 * HPX * 6) / 256, 256, 0, stream>>>(img, w0b, Xhi, Xlo);
  conv0_conv_kernel<<<(2 * HPX * 2) / 256, 256, 0, stream>>>(img, w0a, Xhi, Xlo);

  // ---- launch helpers (pipelined convs; MT=2 @256, MT=1 below)
  auto conv9 = [&](const unsigned short* ih, const unsigned short* il, long wo,
                   unsigned short* oh, unsigned short* ol, int Hs, int logW) {
    int npx = Hs << logW;
    if (npx == HPX)
      conv_pipe_kernel<9, 2, false, false><<<dim3(npx / 128, 1, 2), 256, 0, stream>>>(
          ih, il, packs + wo, nullptr, nullptr, oh, ol, Hs, logW, 1, 0);
    else
      conv_pipe_kernel<9, 1, false, false><<<dim3(npx / 64, 1, 2), 256, 0, stream>>>(
          ih, il, packs + wo, nullptr, nullptr, oh, ol, Hs, logW, 1, 0);
  };
  auto conv9r = [&](const unsigned short* ih, const unsigned short* il, long wo,
                    unsigned short* rh, unsigned short* rl, int Hs, int logW) {
    int npx = Hs << logW;
    if (npx == HPX)
      conv_pipe_kernel<9, 2, true, false><<<dim3(npx / 128, 1, 2), 256, 0, stream>>>(
          ih, il, packs + wo, rh, rl, rh, rl, Hs, logW, 1, 0);
    else
      conv_pipe_kernel<9, 1, true, false><<<dim3(npx / 64, 1, 2), 256, 0, stream>>>(
          ih, il, packs + wo, rh, rl, rh, rl, Hs, logW, 1, 0);
  };
  auto donutC = [&](const unsigned short* ih, const unsigned short* il, long wo,
                    int dil, int ccol) {  // @256 -> concat
    conv_pipe_kernel<8, 2, false, true><<<dim3(512, 1, 2), 256, 0, stream>>>(
        ih, il, packs + wo, nullptr, nullptr, concat, nullptr, 256, 8, dil, ccol);
  };
  auto donutA = [&](const unsigned short* ih, const unsigned short* il, long wo,
                    int dil, unsigned short* oh, unsigned short* ol, int Hs, int logW) {
    int npx = Hs << logW;
    if (npx == HPX)
      conv_pipe_kernel<8, 2, false, false><<<dim3(npx / 128, 1, 2), 256, 0, stream>>>(
          ih, il, packs + wo, nullptr, nullptr, oh, ol, Hs, logW, dil, 0);
    else
      conv_pipe_kernel<8, 1, false, false><<<dim3(npx / 64, 1, 2), 256, 0, stream>>>(
          ih, il, packs + wo, nullptr, nullptr, oh, ol, Hs, logW, dil, 0);
  };
  auto upsC = [&](const unsigned short* ih, const unsigned short* il, long wo,
                  int Hs, int logW, int ccol) {
    ups_mfma_kernel<4><<<dim3(256, 1, 2), 256, 0, stream>>>(
        ih, il, packs + wo, concat, Hs, logW, ccol);
  };
  auto avgp = [&](const unsigned short* ih, const unsigned short* il,
                  unsigned short* oh, unsigned short* ol, int logWo) {
    long total = 2l * (1l << (2 * logWo)) * 8;
    avgpool_nhwc_kernel<<<(int)(total / 256), 256, 0, stream>>>(ih, il, oh, ol, logWo);
  };

  // ---- @256: outs[0], resblock cl10[0], outs[1], resblock cl2[0]
  donutC(Xhi, Xlo, OFF_FIRST, 1, 0);
  conv9(Xhi, Xlo, off_cl10(0), Yhi, Ylo, 256, 8);
  conv9r(Yhi, Ylo, off_cl10(1), Xhi, Xlo, 256, 8);           // base = X @256
  donutC(Xhi, Xlo, off_dilres(0), 3, 64);
  conv9(Xhi, Xlo, off_cl2(0), Yhi, Ylo, 256, 8);
  conv9r(Yhi, Ylo, off_cl2(1), Xhi, Xlo, 256, 8);            // base = X @256

  // ---- i = 0 (dil 5 @256)
  donutA(Xhi, Xlo, off_dil(0), 5, Yhi, Ylo, 256, 8);
  upsC(Yhi, Ylo, off_ups(0), 256, 8, 128);
  avgp(Xhi, Xlo, Yhi, Ylo, 7);                               // base = Y @128
  conv9(Yhi, Ylo, off_cl10(2), Xhi, Xlo, 128, 7);
  conv9r(Xhi, Xlo, off_cl10(3), Yhi, Ylo, 128, 7);           // base = Y @128
  donutA(Yhi, Ylo, off_dilres(1), 6, Xhi, Xlo, 128, 7);
  upsC(Xhi, Xlo, off_ups(1), 128, 7, 192);
  conv9(Yhi, Ylo, off_cl2(2), Xhi, Xlo, 128, 7);
  conv9r(Xhi, Xlo, off_cl2(3), Yhi, Ylo, 128, 7);            // base = Y @128

  // ---- i = 1 (dil 8 @128)
  donutA(Yhi, Ylo, off_dil(1), 8, Xhi, Xlo, 128, 7);
  upsC(Xhi, Xlo, off_ups(1), 128, 7, 256);
  avgp(Yhi, Ylo, Xhi, Xlo, 6);                               // base = X @64
  conv9(Xhi, Xlo, off_cl10(4), Yhi, Ylo, 64, 6);
  conv9r(Yhi, Ylo, off_cl10(5), Xhi, Xlo, 64, 6);            // base = X @64
  donutA(Xhi, Xlo, off_dilres(2), 8, Yhi, Ylo, 64, 6);
  upsC(Yhi, Ylo, off_ups(2), 64, 6, 320);
  conv9(Xhi, Xlo, off_cl2(4), Yhi, Ylo, 64, 6);
  conv9r(Yhi, Ylo, off_cl2(5), Xhi, Xlo, 64, 6);             // base = X @64

  // ---- i = 2 (dil 10 @64)
  donutA(Xhi, Xlo, off_dil(2), 10, Yhi, Ylo, 64, 6);
  upsC(Yhi, Ylo, off_ups(2), 64, 6, 384);
  avgp(Xhi, Xlo, Yhi, Ylo, 5);                               // base = Y @32
  conv9(Yhi, Ylo, off_cl10(6), Xhi, Xlo, 32, 5);
  conv9r(Xhi, Xlo, off_cl10(7), Yhi, Ylo, 32, 5);            // base = Y @32
  donutA(Yhi, Ylo, off_dilres(3), 9, Xhi, Xlo, 32, 5);
  upsC(Xhi, Xlo, off_ups(3), 32, 5, 448);
  conv9(Yhi, Ylo, off_cl2(6), Xhi, Xlo, 32, 5);
  conv9r(Xhi, Xlo, off_cl2(7), Yhi, Ylo, 32, 5);             // base = Y @32

  // ---- i = 3 (dil 11 @32)
  donutA(Yhi, Ylo, off_dil(3), 11, Xhi, Xlo, 32, 5);
  upsC(Xhi, Xlo, off_ups(3), 32, 5, 512);

  // ---- head: 2 px-chunks, h bounced through dead act region
  for (int c = 0; c < 2; c++) {
    out1_gemm_kernel<<<dim3(CHPX / 128, 2), 512, 0, stream>>>(
        concat, w1p, hbuf, c * CHPX);
    out2_gemm_kernel<<<dim3(CHPX / 256, 2), 256, 0, stream>>>(
        hbuf, w2p, w3, (float*)d_out, c * CHPX);
  }
}

// Round 17
// 964.719 us; speedup vs baseline: 1.0669x; 1.0669x over previous
//
#include <hip/hip_runtime.h>
#include <hip/hip_bf16.h>

// ---------------------------------------------------------------------------
// SHINE forward, full bf16-MFMA version with hi/lo-split activations+weights.
// Workspace (222,445,568 B total, unchanged layout):
//   concat : bf16 NHWC [2][65536][576]          150,994,944 B
//   Xhi,Xlo,Yhi,Ylo : bf16 NHWC [2][65536][64]  4 x 16,777,216 B
//   packs  : conv B-frags (hi,lo)                 3,604,480 B
//   w1p    : head W1 frags                          663,552 B
//   w2p    : head W2 frags                           73,728 B
// R17: out1_gemm v5 = R15 structure (256 thr, 64 px, mt-split {5,5,4,4},
//      single 36.9KB stage, stride-300 transpose) + A-fragment register
//      DOUBLE-BUFFER (load a(kt+1) during compute(kt)) -> no exposed global
//      latency in the kt loop. R16's 512-thread variant reverted (regressed:
//      8-wave barriers + divergent staging). Bit-identical math.
// ---------------------------------------------------------------------------

#define HPX 65536   // 256*256
#define FCH 64
#define CHPX 32768  // head px-chunk

typedef __attribute__((ext_vector_type(8))) short  short8;
typedef __attribute__((ext_vector_type(4))) float  floatx4;

__device__ __forceinline__ float gelu_f(float x) {
  return 0.5f * x * (1.0f + erff(x * 0.70710678118654752440f));
}
__device__ __forceinline__ unsigned short f2bf(float x) {  // RNE
  unsigned u = __float_as_uint(x);
  unsigned r = (u + 0x7FFFu + ((u >> 16) & 1u)) >> 16;
  return (unsigned short)r;
}
__device__ __forceinline__ float bf2f(unsigned short h) {
  return __uint_as_float(((unsigned)h) << 16);
}

// ---------------- conv0 part A: channels 0..47 = gelu(w0b[c] * target)
__global__ __launch_bounds__(256) void conv0_elem_kernel(
    const float* __restrict__ img,   // [2][5][256][256]
    const float* __restrict__ w0b,   // [48]
    unsigned short* __restrict__ ohi,  // [2][65536][64]
    unsigned short* __restrict__ olo)
{
  int t = blockIdx.x * 256 + threadIdx.x;     // over 2*HPX*6 = 786432
  int cg = t % 6;
  int pn = t / 6;                              // n*HPX + px
  int px = pn & (HPX - 1);
  int n  = pn >> 16;
  float x = img[(long)n * 5 * HPX + 2 * HPX + px];
  short8 oh, ol;
  #pragma unroll
  for (int j = 0; j < 8; j++) {
    int c = cg * 8 + j;
    float v = gelu_f(w0b[c] * x);
    unsigned short hb = f2bf(v);
    oh[j] = (short)hb;
    ol[j] = (short)f2bf(v - bf2f(hb));
  }
  long o = ((long)pn) * 64 + cg * 8;
  *(short8*)&ohi[o] = oh;
  *(short8*)&olo[o] = ol;
}

// ---------------- conv0 part B: channels 48..63 = gelu(3x3 conv over 4 feats)
__global__ __launch_bounds__(256) void conv0_conv_kernel(
    const float* __restrict__ img,   // [2][5][256][256]
    const float* __restrict__ w0a,   // [16][4][3][3]
    unsigned short* __restrict__ ohi,
    unsigned short* __restrict__ olo)
{
  int t = blockIdx.x * 256 + threadIdx.x;     // over 2*HPX*2 = 262144
  int cg = t & 1;
  int pn = t >> 1;
  int px = pn & (HPX - 1);
  int n  = pn >> 16;
  int y = px >> 8, x = px & 255;
  const float* im = img + (long)n * 5 * HPX;
  const int map4[4] = {0, 1, 3, 4};
  float vreg[36];
  #pragma unroll
  for (int fi = 0; fi < 4; fi++)
    #pragma unroll
    for (int ky = 0; ky < 3; ky++)
      #pragma unroll
      for (int kx = 0; kx < 3; kx++) {
        int yy = y + ky - 1, xx = x + kx - 1;
        bool ok = ((unsigned)yy < 256u) && ((unsigned)xx < 256u);
        vreg[(fi * 3 + ky) * 3 + kx] =
            ok ? im[(long)map4[fi] * HPX + yy * 256 + xx] : 0.0f;
      }
  short8 oh, ol;
  #pragma unroll
  for (int j = 0; j < 8; j++) {
    int co = cg * 8 + j;                       // 0..15 -> output ch 48+co
    const float* wr = w0a + co * 36;
    float r = 0.0f;
    #pragma unroll
    for (int q = 0; q < 36; q++) r = fmaf(wr[q], vreg[q], r);
    float v = gelu_f(r);
    unsigned short hb = f2bf(v);
    oh[j] = (short)hb;
    ol[j] = (short)f2bf(v - bf2f(hb));
  }
  long o = ((long)pn) * 64 + 48 + cg * 8;
  *(short8*)&ohi[o] = oh;
  *(short8*)&olo[o] = ol;
}

// ---------------- batched conv-weight packing into MFMA B-frags (hi,lo)
struct JobArr { int4 j[29]; };   // {src_sel, src_off, ntaps, dst_off}

__global__ __launch_bounds__(256) void pack_conv_kernel(
    const float* __restrict__ cl10, const float* __restrict__ cl2,
    const float* __restrict__ first_p, const float* __restrict__ dilres_p,
    const float* __restrict__ dil_p, const float* __restrict__ ups_w,
    unsigned short* __restrict__ packs, JobArr jobs)
{
  int4 jb = jobs.j[blockIdx.y];
  int ntaps = jb.z;
  int idx = blockIdx.x * 256 + threadIdx.x;
  if (idx >= ntaps * 8192) return;
  int j  = idx & 7;
  int l  = (idx >> 3) & 63;
  int s  = (idx >> 9) & 1;
  int nt = (idx >> 10) & 3;
  int kt = (idx >> 12) & 1;
  int tap = idx >> 13;
  int oc = nt * 16 + (l & 15);
  int ci = kt * 32 + (l >> 4) * 8 + j;
  const float* src;
  switch (jb.x) {
    case 0: src = cl10; break;
    case 1: src = cl2; break;
    case 2: src = first_p; break;
    case 3: src = dilres_p; break;
    case 4: src = dil_p; break;
    default: src = ups_w; break;
  }
  float w = src[jb.y + (oc * 64 + ci) * ntaps + tap];
  unsigned short hi = f2bf(w);
  unsigned short v = (s == 0) ? hi : f2bf(w - bf2f(hi));
  packs[jb.w + idx] = v;
}

// ---------------- head weight packing (hi+lo)
__global__ __launch_bounds__(256) void pack_w1_kernel(
    const float* __restrict__ w1, unsigned short* __restrict__ w1p)
{
  int t = blockIdx.x * 256 + threadIdx.x;      // 18*18*512
  if (t >= 18 * 18 * 512) return;
  int j = t & 7, l = (t >> 3) & 63;
  int mt = (t >> 9) % 18, kt = (t >> 9) / 18;
  int oc = mt * 16 + (l & 15);
  int k  = kt * 32 + (l >> 4) * 8 + j;
  float w = w1[oc * 576 + k];
  unsigned short hi = f2bf(w);
  unsigned short lo = f2bf(w - bf2f(hi));
  long base = ((long)(kt * 18 + mt) * 2) * 512 + l * 8 + j;
  w1p[base] = hi;
  w1p[base + 512] = lo;
}
__global__ __launch_bounds__(256) void pack_w2_kernel(
    const float* __restrict__ w2, unsigned short* __restrict__ w2p)
{
  int t = blockIdx.x * 256 + threadIdx.x;      // 9*4*512
  if (t >= 9 * 4 * 512) return;
  int j = t & 7, l = (t >> 3) & 63;
  int ot = (t >> 9) % 4, kt = (t >> 9) / 4;
  int oc = ot * 16 + (l & 15);
  int k  = kt * 32 + (l >> 4) * 8 + j;
  float w = w2[oc * 288 + k];
  unsigned short hi = f2bf(w);
  unsigned short lo = f2bf(w - bf2f(hi));
  long base = ((long)(kt * 4 + ot) * 2) * 512 + l * 8 + j;
  w2p[base] = hi;
  w2p[base + 512] = lo;
}

// ---------------- software-pipelined MFMA conv (implicit GEMM, 16x16x32 bf16)
template <int NTAPS, int MT, bool RESID, bool TO_CONCAT>
__global__ __launch_bounds__(256) void conv_pipe_kernel(
    const unsigned short* __restrict__ in_hi,   // NHWC [n][npx_in][64]
    const unsigned short* __restrict__ in_lo,
    const unsigned short* __restrict__ wp,      // packed frags
    const unsigned short* __restrict__ res_hi,
    const unsigned short* __restrict__ res_lo,
    unsigned short* __restrict__ out_hi,        // act hi or concat
    unsigned short* __restrict__ out_lo,
    int Hs, int logW, int dil, int ccol)
{
  __shared__ short8 wst[2][1024];               // 2 x 16 KB double buffer
  __shared__ float  ftb[4][16][65];             // per-wave f32 transpose tiles
  const int tid  = threadIdx.x;
  const int lane = tid & 63;
  const int wave = tid >> 6;
  const int row  = lane & 15;
  const int g    = lane >> 4;
  const int n    = blockIdx.z;
  const int Ws   = 1 << logW;
  const int npx_in = Hs << logW;
  const int opx0 = blockIdx.x * (64 * MT) + wave * (16 * MT);

  const unsigned short* ihi = in_hi + (long)n * npx_in * 64;
  const unsigned short* ilo = in_lo + (long)n * npx_in * 64;
  const short8* wpv = (const short8*)wp;

  int ry[MT], rx[MT];
  #pragma unroll
  for (int mt = 0; mt < MT; mt++) {
    int p = opx0 + mt * 16 + row;
    ry[mt] = p >> logW;
    rx[mt] = p & (Ws - 1);
  }

  floatx4 acc[MT][4];
  #pragma unroll
  for (int mt = 0; mt < MT; mt++)
    #pragma unroll
    for (int nt = 0; nt < 4; nt++) acc[mt][nt] = (floatx4){0.f, 0.f, 0.f, 0.f};

  const short8 zz = {0, 0, 0, 0, 0, 0, 0, 0};
  short8 sreg[4];
  short8 ahA[MT][2], alA[MT][2], ahB[MT][2], alB[MT][2];

  auto stage_issue = [&](int t) {
    #pragma unroll
    for (int p = 0; p < 4; p++)
      sreg[p] = wpv[(long)t * 1024 + tid + p * 256];
  };
  auto stage_write = [&](int b) {
    #pragma unroll
    for (int p = 0; p < 4; p++)
      wst[b][tid + p * 256] = sreg[p];
  };
  auto a_load = [&](short8 (&ah)[MT][2], short8 (&al)[MT][2], int t) {
    const int kk  = (NTAPS == 9) ? t : (t < 4 ? t : t + 1);
    const int dyd = (kk / 3 - 1) * dil, dxd = (kk % 3 - 1) * dil;
    #pragma unroll
    for (int mt = 0; mt < MT; mt++) {
      int yy = ry[mt] + dyd, xx = rx[mt] + dxd;
      bool ok = ((unsigned)yy < (unsigned)Hs) && ((unsigned)xx < (unsigned)Ws);
      long base = ok ? (long)((yy << logW) + xx) * 64 : 0;
      #pragma unroll
      for (int kt = 0; kt < 2; kt++) {
        long a = base + kt * 32 + g * 8;
        short8 h = *(const short8*)(ihi + a);
        short8 l = *(const short8*)(ilo + a);
        ah[mt][kt] = ok ? h : zz;
        al[mt][kt] = ok ? l : zz;
      }
    }
  };
  auto compute = [&](int b, short8 (&ah)[MT][2], short8 (&al)[MT][2]) {
    #pragma unroll
    for (int kt = 0; kt < 2; kt++)
      #pragma unroll
      for (int nt = 0; nt < 4; nt++) {
        short8 bh = wst[b][(kt * 4 + nt) * 128 + lane];
        short8 bl = wst[b][(kt * 4 + nt) * 128 + 64 + lane];
        #pragma unroll
        for (int mt = 0; mt < MT; mt++) {
          acc[mt][nt] = __builtin_amdgcn_mfma_f32_16x16x32_bf16(ah[mt][kt], bh, acc[mt][nt], 0, 0, 0);
          acc[mt][nt] = __builtin_amdgcn_mfma_f32_16x16x32_bf16(ah[mt][kt], bl, acc[mt][nt], 0, 0, 0);
          acc[mt][nt] = __builtin_amdgcn_mfma_f32_16x16x32_bf16(al[mt][kt], bh, acc[mt][nt], 0, 0, 0);
        }
      }
  };

  // prologue: stage + A for tap 0
  stage_issue(0);
  a_load(ahA, alA, 0);
  stage_write(0);
  __syncthreads();

  #pragma unroll
  for (int tt = 0; tt < NTAPS; tt++) {
    const int b = tt & 1;
    if (tt + 1 < NTAPS) {
      stage_issue(tt + 1);                       // global loads, early
      if ((tt & 1) == 0) a_load(ahB, alB, tt + 1);
      else               a_load(ahA, alA, tt + 1);
    }
    if ((tt & 1) == 0) compute(b, ahA, alA);     // hides the loads above
    else               compute(b, ahB, alB);
    if (tt + 1 < NTAPS) {
      stage_write(b ^ 1);                        // write-late into other buf
      __syncthreads();                           // ONE barrier per tap
    }
  }

  // epilogue: acc -> f32 LDS tile -> (+coalesced resid) -> gelu -> short8 out
  #pragma unroll
  for (int mt = 0; mt < MT; mt++) {
    __builtin_amdgcn_wave_barrier();
    #pragma unroll
    for (int nt = 0; nt < 4; nt++)
      #pragma unroll
      for (int r = 0; r < 4; r++)
        ftb[wave][g * 4 + r][nt * 16 + row] = acc[mt][nt][r];
    __builtin_amdgcn_wave_barrier();
    const int pxb = opx0 + mt * 16;
    const int pxl = lane >> 2;
    #pragma unroll
    for (int it = 0; it < 2; it++) {
      const int ch = (lane & 3) + it * 4;
      float vv[8];
      #pragma unroll
      for (int j = 0; j < 8; j++) vv[j] = ftb[wave][pxl][ch * 8 + j];
      if (RESID) {
        long rb = ((long)n * npx_in + pxb + pxl) * 64 + ch * 8;
        short8 rh = *(const short8*)(res_hi + rb);
        short8 rl = *(const short8*)(res_lo + rb);
        #pragma unroll
        for (int j = 0; j < 8; j++)
          vv[j] += bf2f((unsigned short)rh[j]) + bf2f((unsigned short)rl[j]);
      }
      short8 oh8, ol8;
      #pragma unroll
      for (int j = 0; j < 8; j++) {
        float v = gelu_f(vv[j]);
        unsigned short hb = f2bf(v);
        oh8[j] = (short)hb;
        ol8[j] = (short)f2bf(v - bf2f(hb));
      }
      if (TO_CONCAT) {
        *(short8*)&out_hi[((long)n * HPX + pxb + pxl) * 576 + ccol + ch * 8] = oh8;
      } else {
        *(short8*)&out_hi[((long)n * npx_in + pxb + pxl) * 64 + ch * 8] = oh8;
        *(short8*)&out_lo[((long)n * npx_in + pxb + pxl) * 64 + ch * 8] = ol8;
      }
    }
  }
}

// ---------------- bilinear-upsample 1x1 conv -> concat (coalesced epilogue)
template <int MT>
__global__ __launch_bounds__(256) void ups_mfma_kernel(
    const unsigned short* __restrict__ in_hi,   // NHWC [n][npx_in][64]
    const unsigned short* __restrict__ in_lo,
    const unsigned short* __restrict__ wp,      // packed frags (1 tap)
    unsigned short* __restrict__ outc,          // concat
    int Hs, int logW, int ccol)
{
  __shared__ short8 wst[1024];                  // 16 KB: one tap's 16 frags
  __shared__ unsigned short tb[4][16][76];
  const int tid  = threadIdx.x;
  const int lane = threadIdx.x & 63;
  const int wave = threadIdx.x >> 6;
  const int row  = lane & 15;
  const int g    = lane >> 4;
  const int n    = blockIdx.z;
  const int npx_in = Hs << logW;
  const int opx0 = blockIdx.x * (64 * MT) + wave * (16 * MT);

  const unsigned short* ihi = in_hi + (long)n * npx_in * 64;
  const unsigned short* ilo = in_lo + (long)n * npx_in * 64;
  const short8* wpv = (const short8*)wp;

  int b00[MT], b01[MT], b10[MT], b11[MT];
  float bwx[MT], bwy[MT];
  #pragma unroll
  for (int mt = 0; mt < MT; mt++) {
    int p = opx0 + mt * 16 + row;
    int Y = p >> 8, X = p & 255;
    float sc = (float)Hs * (1.0f / 256.0f);
    float fy = ((float)Y + 0.5f) * sc - 0.5f;
    float fx = ((float)X + 0.5f) * sc - 0.5f;
    int y0 = (int)floorf(fy), x0 = (int)floorf(fx);
    bwy[mt] = fy - (float)y0; bwx[mt] = fx - (float)x0;
    int y0c = min(max(y0, 0), Hs - 1), y1c = min(max(y0 + 1, 0), Hs - 1);
    int x0c = min(max(x0, 0), Hs - 1), x1c = min(max(x0 + 1, 0), Hs - 1);
    b00[mt] = (y0c * Hs + x0c) * 64; b01[mt] = (y0c * Hs + x1c) * 64;
    b10[mt] = (y1c * Hs + x0c) * 64; b11[mt] = (y1c * Hs + x1c) * 64;
  }

  floatx4 acc[MT][4];
  #pragma unroll
  for (int mt = 0; mt < MT; mt++)
    #pragma unroll
    for (int nt = 0; nt < 4; nt++) acc[mt][nt] = (floatx4){0.f, 0.f, 0.f, 0.f};

  #pragma unroll
  for (int p = 0; p < 4; p++)
    wst[tid + p * 256] = wpv[tid + p * 256];
  __syncthreads();

  #pragma unroll
  for (int kt = 0; kt < 2; kt++) {
    const int ko = kt * 32 + g * 8;
    short8 ah[MT], al[MT];
    #pragma unroll
    for (int mt = 0; mt < MT; mt++) {
      short8 h00 = *(const short8*)(ihi + b00[mt] + ko);
      short8 l00 = *(const short8*)(ilo + b00[mt] + ko);
      short8 h01 = *(const short8*)(ihi + b01[mt] + ko);
      short8 l01 = *(const short8*)(ilo + b01[mt] + ko);
      short8 h10 = *(const short8*)(ihi + b10[mt] + ko);
      short8 l10 = *(const short8*)(ilo + b10[mt] + ko);
      short8 h11 = *(const short8*)(ihi + b11[mt] + ko);
      short8 l11 = *(const short8*)(ilo + b11[mt] + ko);
      short8 hh, ll;
      #pragma unroll
      for (int j = 0; j < 8; j++) {
        float v00 = bf2f((unsigned short)h00[j]) + bf2f((unsigned short)l00[j]);
        float v01 = bf2f((unsigned short)h01[j]) + bf2f((unsigned short)l01[j]);
        float v10 = bf2f((unsigned short)h10[j]) + bf2f((unsigned short)l10[j]);
        float v11 = bf2f((unsigned short)h11[j]) + bf2f((unsigned short)l11[j]);
        float v0 = v00 + bwx[mt] * (v01 - v00);
        float v1 = v10 + bwx[mt] * (v11 - v10);
        float v  = v0 + bwy[mt] * (v1 - v0);
        unsigned short hb = f2bf(v);
        hh[j] = (short)hb;
        ll[j] = (short)f2bf(v - bf2f(hb));
      }
      ah[mt] = hh; al[mt] = ll;
    }
    #pragma unroll
    for (int nt = 0; nt < 4; nt++) {
      short8 bh = wst[(kt * 4 + nt) * 2 * 64 + lane];
      short8 bl = wst[((kt * 4 + nt) * 2 + 1) * 64 + lane];
      #pragma unroll
      for (int mt = 0; mt < MT; mt++) {
        acc[mt][nt] = __builtin_amdgcn_mfma_f32_16x16x32_bf16(ah[mt], bh, acc[mt][nt], 0, 0, 0);
        acc[mt][nt] = __builtin_amdgcn_mfma_f32_16x16x32_bf16(ah[mt], bl, acc[mt][nt], 0, 0, 0);
        acc[mt][nt] = __builtin_amdgcn_mfma_f32_16x16x32_bf16(al[mt], bh, acc[mt][nt], 0, 0, 0);
      }
    }
  }

  #pragma unroll
  for (int mt = 0; mt < MT; mt++) {
    __builtin_amdgcn_wave_barrier();
    #pragma unroll
    for (int nt = 0; nt < 4; nt++)
      #pragma unroll
      for (int r = 0; r < 4; r++)
        tb[wave][g * 4 + r][nt * 16 + row] = f2bf(gelu_f(acc[mt][nt][r]));
    __builtin_amdgcn_wave_barrier();
    const int pxb = opx0 + mt * 16;
    const int pxl = lane >> 2;
    #pragma unroll
    for (int it = 0; it < 2; it++) {
      int ch = (lane & 3) + it * 4;
      short8 v8 = *(const short8*)&tb[wave][pxl][ch * 8];
      *(short8*)&outc[((long)n * HPX + pxb + pxl) * 576 + ccol + ch * 8] = v8;
    }
  }
}

// ---------------- 2x2 average pool, NHWC hi/lo -> NHWC hi/lo
__global__ __launch_bounds__(256) void avgpool_nhwc_kernel(
    const unsigned short* __restrict__ ihi, const unsigned short* __restrict__ ilo,
    unsigned short* __restrict__ ohi, unsigned short* __restrict__ olo,
    int logWo)
{
  const int lognpo = 2 * logWo;
  long t = (long)blockIdx.x * 256 + threadIdx.x;   // over 2*npo*8
  int cg = (int)(t & 7);
  int p  = (int)((t >> 3) & ((1 << lognpo) - 1));
  int n  = (int)(t >> (3 + lognpo));
  int y = p >> logWo, x = p & ((1 << logWo) - 1);
  int Wi = 2 << logWo;
  long ib = ((long)n * (4 << lognpo) + (long)(2 * y) * Wi + 2 * x) * 64 + cg * 8;
  short8 h00 = *(const short8*)(ihi + ib);
  short8 h01 = *(const short8*)(ihi + ib + 64);
  short8 h10 = *(const short8*)(ihi + ib + (long)Wi * 64);
  short8 h11 = *(const short8*)(ihi + ib + (long)Wi * 64 + 64);
  short8 l00 = *(const short8*)(ilo + ib);
  short8 l01 = *(const short8*)(ilo + ib + 64);
  short8 l10 = *(const short8*)(ilo + ib + (long)Wi * 64);
  short8 l11 = *(const short8*)(ilo + ib + (long)Wi * 64 + 64);
  short8 oh, ol;
  #pragma unroll
  for (int j = 0; j < 8; j++) {
    float v = 0.25f * ((bf2f((unsigned short)h00[j]) + bf2f((unsigned short)l00[j])) +
                       (bf2f((unsigned short)h01[j]) + bf2f((unsigned short)l01[j])) +
                       (bf2f((unsigned short)h10[j]) + bf2f((unsigned short)l10[j])) +
                       (bf2f((unsigned short)h11[j]) + bf2f((unsigned short)l11[j])));
    unsigned short hb = f2bf(v);
    oh[j] = (short)hb;
    ol[j] = (short)f2bf(v - bf2f(hb));
  }
  long ob = (((long)n << lognpo) + p) * 64 + cg * 8;
  *(short8*)(ohi + ob) = oh;
  *(short8*)(olo + ob) = ol;
}

// ---------------- head stage 1 GEMM v5: h = gelu(W1 @ concat), one px-chunk
// R15 structure (64 px/block, mt-split {5,5,4,4}, single 36.9KB stage,
// stride-300 transpose) + A-fragment register double-buffer: a(kt+1) loaded
// alongside the weight prefetch during compute(kt) -> no exposed global
// latency in the kt loop. Math order identical (same absmax).
__global__ __launch_bounds__(256) void out1_gemm_kernel(
    const unsigned short* __restrict__ v,       // concat NHWC [2][65536][576]
    const unsigned short* __restrict__ w1p,
    unsigned short* __restrict__ h,             // [2][CHPX][288] bf16
    int cpx)
{
  __shared__ short8 ws8[2400];                  // 38,400 B (stage / transpose)
  const int tid  = threadIdx.x;
  const int lane = tid & 63;
  const int wave = tid >> 6;
  const int row  = lane & 15;
  const int g    = lane >> 4;
  const int n    = blockIdx.y;
  const int px0  = cpx + blockIdx.x * 64;       // absolute px
  const int mtb  = (wave < 2) ? wave * 5 : 10 + (wave - 2) * 4;
  const int MTN  = (wave < 2) ? 5 : 4;
  const short8* w1v = (const short8*)w1p;
  const unsigned short* vb = v + ((long)n * HPX + px0) * 576;

  floatx4 acc[4][5];
  #pragma unroll
  for (int t = 0; t < 4; t++)
    #pragma unroll
    for (int m = 0; m < 5; m++) acc[t][m] = (floatx4){0.f, 0.f, 0.f, 0.f};

  short8 sreg[9];
  short8 aA[4], aB[4];
  auto stage_issue = [&](int kt) {
    #pragma unroll
    for (int p = 0; p < 9; p++)
      sreg[p] = w1v[kt * 2304 + tid + p * 256];
  };
  auto stage_write = [&]() {
    #pragma unroll
    for (int p = 0; p < 9; p++)
      ws8[tid + p * 256] = sreg[p];
  };
  auto a_load = [&](short8 (&a)[4], int kt) {
    #pragma unroll
    for (int t = 0; t < 4; t++)
      a[t] = *(const short8*)(vb + (long)(t * 16 + row) * 576 + kt * 32 + g * 8);
  };
  auto compute = [&](short8 (&a)[4]) {
    #pragma unroll
    for (int m = 0; m < 5; m++) {
      if (m < MTN) {
        short8 bh = ws8[((mtb + m) * 2 + 0) * 64 + lane];
        short8 bl = ws8[((mtb + m) * 2 + 1) * 64 + lane];
        #pragma unroll
        for (int t = 0; t < 4; t++) {
          acc[t][m] = __builtin_amdgcn_mfma_f32_16x16x32_bf16(a[t], bh, acc[t][m], 0, 0, 0);
          acc[t][m] = __builtin_amdgcn_mfma_f32_16x16x32_bf16(a[t], bl, acc[t][m], 0, 0, 0);
        }
      }
    }
  };

  // prologue: stage + A for kt 0
  stage_issue(0);
  a_load(aA, 0);
  stage_write();
  __syncthreads();

  #pragma unroll 2
  for (int kt = 0; kt < 18; kt++) {
    if (kt + 1 < 18) {
      stage_issue(kt + 1);                       // weight loads, early
      if ((kt & 1) == 0) a_load(aB, kt + 1);     // A loads, early
      else               a_load(aA, kt + 1);
    }
    if ((kt & 1) == 0) compute(aA);              // zero exposed global latency
    else               compute(aB);
    if (kt + 1 < 18) {
      __syncthreads();                           // all waves done reading ws8
      stage_write();                             // write-late from registers
      __syncthreads();                           // ws8 ready for kt+1
    }
  }

  // epilogue: gelu -> bf16 -> LDS [64][300] -> coalesced h writes
  __syncthreads();
  unsigned short* hs2 = (unsigned short*)ws8;
  #pragma unroll
  for (int m = 0; m < 5; m++) {
    if (m < MTN) {
      #pragma unroll
      for (int t = 0; t < 4; t++)
        #pragma unroll
        for (int r = 0; r < 4; r++)
          hs2[(t * 16 + g * 4 + r) * 300 + (mtb + m) * 16 + row] =
              f2bf(gelu_f(acc[t][m][r]));
    }
  }
  __syncthreads();
  #pragma unroll
  for (int p = 0; p < 9; p++) {
    int li = tid + p * 256;                      // 2304 chunks of 16B
    int px = li / 36, c16 = li % 36;
    short8 v8 = *(const short8*)&hs2[px * 300 + c16 * 8];
    *(short8*)&h[((long)n * CHPX + (px0 - cpx) + px) * 288 + c16 * 8] = v8;
  }
}

// ---------------- head stage 2: out = w3 . gelu(W2 @ h), one px-chunk
__global__ __launch_bounds__(256) void out2_gemm_kernel(
    const unsigned short* __restrict__ h,       // [2][CHPX][288] bf16
    const unsigned short* __restrict__ w2p,
    const float* __restrict__ w3,               // [64]
    float* __restrict__ out,                    // [2][65536]
    int cpx)
{
  __shared__ short8 w2s[4608];                  // 73,728 B, whole w2p
  const int tid  = threadIdx.x;
  const int lane = tid & 63;
  const int wave = tid >> 6;
  const int row  = lane & 15;
  const int g    = lane >> 4;
  const int n    = blockIdx.y;
  const int pxc  = blockIdx.x * 256 + wave * 64; // px within chunk
  const short8* w2v = (const short8*)w2p;

  #pragma unroll
  for (int p = 0; p < 18; p++)
    w2s[tid + p * 256] = w2v[tid + p * 256];
  __syncthreads();

  floatx4 acc2[4][4];
  #pragma unroll
  for (int t = 0; t < 4; t++)
    #pragma unroll
    for (int ot = 0; ot < 4; ot++) acc2[t][ot] = (floatx4){0.f, 0.f, 0.f, 0.f};

  for (int kt = 0; kt < 9; kt++) {
    short8 a[4];
    #pragma unroll
    for (int t = 0; t < 4; t++)
      a[t] = *(const short8*)&h[((long)n * CHPX + pxc + t * 16 + row) * 288 +
                                kt * 32 + g * 8];
    #pragma unroll
    for (int ot = 0; ot < 4; ot++) {
      short8 bh = w2s[((kt * 4 + ot) * 2 + 0) * 64 + lane];
      short8 bl = w2s[((kt * 4 + ot) * 2 + 1) * 64 + lane];
      #pragma unroll
      for (int t = 0; t < 4; t++) {
        acc2[t][ot] = __builtin_amdgcn_mfma_f32_16x16x32_bf16(a[t], bh, acc2[t][ot], 0, 0, 0);
        acc2[t][ot] = __builtin_amdgcn_mfma_f32_16x16x32_bf16(a[t], bl, acc2[t][ot], 0, 0, 0);
      }
    }
  }

  float w3r[4];
  #pragma unroll
  for (int ot = 0; ot < 4; ot++) w3r[ot] = w3[ot * 16 + row];
  #pragma unroll
  for (int t = 0; t < 4; t++) {
    float r[4] = {0.f, 0.f, 0.f, 0.f};
    #pragma unroll
    for (int ot = 0; ot < 4; ot++)
      #pragma unroll
      for (int rr = 0; rr < 4; rr++)
        r[rr] = fmaf(w3r[ot], gelu_f(acc2[t][ot][rr]), r[rr]);
    #pragma unroll
    for (int rr = 0; rr < 4; rr++) {
      r[rr] += __shfl_xor(r[rr], 1);
      r[rr] += __shfl_xor(r[rr], 2);
      r[rr] += __shfl_xor(r[rr], 4);
      r[rr] += __shfl_xor(r[rr], 8);
    }
    if (row == 0) {
      int px = cpx + pxc + t * 16 + g * 4;
      #pragma unroll
      for (int rr = 0; rr < 4; rr++)
        out[(long)n * HPX + px + rr] = r[rr];
    }
  }
}

// ---------------------------------------------------------------------------
extern "C" void kernel_launch(void* const* d_in, const int* in_sizes, int n_in,
                              void* d_out, int out_size, void* d_ws, size_t ws_size,
                              hipStream_t stream) {
  const float* img      = (const float*)d_in[0];
  const float* w0a      = (const float*)d_in[1];
  const float* w0b      = (const float*)d_in[2];
  const float* first_p  = (const float*)d_in[3];
  const float* cl10     = (const float*)d_in[4];   // [4][2][64][64][9]
  const float* cl2      = (const float*)d_in[5];
  const float* dil_p    = (const float*)d_in[6];   // [4][64][64][8]
  const float* dilres_p = (const float*)d_in[7];
  const float* ups_w    = (const float*)d_in[8];   // [4][64][64]
  const float* w1       = (const float*)d_in[9];   // [288][576]
  const float* w2       = (const float*)d_in[10];  // [64][288]
  const float* w3       = (const float*)d_in[11];  // [64]

  const size_t CONCAT_B = 150994944ul;             // 2*65536*576*2
  const size_t ACT_B    = 16777216ul;              // 2*65536*64*2 per plane
  const size_t PACKS_B  = 3604480ul;               // 1,802,240 elems
  const size_t W1P_B    = 663552ul;
  const size_t W2P_B    = 73728ul;
  const size_t NEED = CONCAT_B + 4 * ACT_B + PACKS_B + W1P_B + W2P_B; // 222,445,568

  if (ws_size < NEED) {
    hipMemsetAsync(d_out, 0, (size_t)out_size * 4, stream);
    return;
  }

  char* wsb = (char*)d_ws;
  unsigned short* concat = (unsigned short*)wsb;
  unsigned short* Xhi = (unsigned short*)(wsb + CONCAT_B);
  unsigned short* Xlo = (unsigned short*)(wsb + CONCAT_B + ACT_B);
  unsigned short* Yhi = (unsigned short*)(wsb + CONCAT_B + 2 * ACT_B);
  unsigned short* Ylo = (unsigned short*)(wsb + CONCAT_B + 3 * ACT_B);
  unsigned short* packs = (unsigned short*)(wsb + CONCAT_B + 4 * ACT_B);
  unsigned short* w1p = (unsigned short*)(wsb + CONCAT_B + 4 * ACT_B + PACKS_B);
  unsigned short* w2p = (unsigned short*)(wsb + CONCAT_B + 4 * ACT_B + PACKS_B + W1P_B);
  unsigned short* hbuf = Xhi;   // head h buffer reuses dead act region

  // pack-destination offsets (elems)
  auto off_cl10   = [](int c) { return (long)c * 73728; };
  auto off_cl2    = [](int c) { return 589824l + (long)c * 73728; };
  const long OFF_FIRST = 1179648;
  auto off_dilres = [](int k) { return 1245184l + (long)k * 65536; };
  auto off_dil    = [](int k) { return 1507328l + (long)k * 65536; };
  auto off_ups    = [](int k) { return 1769472l + (long)k * 8192; };

  // ---- weight packing
  JobArr jobs;
  for (int c = 0; c < 8; c++) jobs.j[c]     = {0, c * 36864, 9, (int)off_cl10(c)};
  for (int c = 0; c < 8; c++) jobs.j[8 + c] = {1, c * 36864, 9, (int)off_cl2(c)};
  jobs.j[16] = {2, 0, 8, (int)OFF_FIRST};
  for (int k = 0; k < 4; k++) jobs.j[17 + k] = {3, k * 32768, 8, (int)off_dilres(k)};
  for (int k = 0; k < 4; k++) jobs.j[21 + k] = {4, k * 32768, 8, (int)off_dil(k)};
  for (int k = 0; k < 4; k++) jobs.j[25 + k] = {5, k * 4096, 1, (int)off_ups(k)};
  pack_conv_kernel<<<dim3(288, 29), 256, 0, stream>>>(
      cl10, cl2, first_p, dilres_p, dil_p, ups_w, packs, jobs);
  pack_w1_kernel<<<(18 * 18 * 512 + 255) / 256, 256, 0, stream>>>(w1, w1p);
  pack_w2_kernel<<<(9 * 4 * 512 + 255) / 256, 256, 0, stream>>>(w2, w2p);

  // ---- conv0 -> X @256 (elementwise part + 3x3 part)
  conv0_elem_kernel<<<(2 * HPX * 6) / 256, 256, 0, stream>>>(img, w0b, Xhi, Xlo);
  conv0_conv_kernel<<<(2 * HPX * 2) / 256, 256, 0, stream>>>(img, w0a, Xhi, Xlo);

  // ---- launch helpers (pipelined convs; MT=2 @256, MT=1 below)
  auto conv9 = [&](const unsigned short* ih, const unsigned short* il, long wo,
                   unsigned short* oh, unsigned short* ol, int Hs, int logW) {
    int npx = Hs << logW;
    if (npx == HPX)
      conv_pipe_kernel<9, 2, false, false><<<dim3(npx / 128, 1, 2), 256, 0, stream>>>(
          ih, il, packs + wo, nullptr, nullptr, oh, ol, Hs, logW, 1, 0);
    else
      conv_pipe_kernel<9, 1, false, false><<<dim3(npx / 64, 1, 2), 256, 0, stream>>>(
          ih, il, packs + wo, nullptr, nullptr, oh, ol, Hs, logW, 1, 0);
  };
  auto conv9r = [&](const unsigned short* ih, const unsigned short* il, long wo,
                    unsigned short* rh, unsigned short* rl, int Hs, int logW) {
    int npx = Hs << logW;
    if (npx == HPX)
      conv_pipe_kernel<9, 2, true, false><<<dim3(npx / 128, 1, 2), 256, 0, stream>>>(
          ih, il, packs + wo, rh, rl, rh, rl, Hs, logW, 1, 0);
    else
      conv_pipe_kernel<9, 1, true, false><<<dim3(npx / 64, 1, 2), 256, 0, stream>>>(
          ih, il, packs + wo, rh, rl, rh, rl, Hs, logW, 1, 0);
  };
  auto donutC = [&](const unsigned short* ih, const unsigned short* il, long wo,
                    int dil, int ccol) {  // @256 -> concat
    conv_pipe_kernel<8, 2, false, true><<<dim3(512, 1, 2), 256, 0, stream>>>(
        ih, il, packs + wo, nullptr, nullptr, concat, nullptr, 256, 8, dil, ccol);
  };
  auto donutA = [&](const unsigned short* ih, const unsigned short* il, long wo,
                    int dil, unsigned short* oh, unsigned short* ol, int Hs, int logW) {
    int npx = Hs << logW;
    if (npx == HPX)
      conv_pipe_kernel<8, 2, false, false><<<dim3(npx / 128, 1, 2), 256, 0, stream>>>(
          ih, il, packs + wo, nullptr, nullptr, oh, ol, Hs, logW, dil, 0);
    else
      conv_pipe_kernel<8, 1, false, false><<<dim3(npx / 64, 1, 2), 256, 0, stream>>>(
          ih, il, packs + wo, nullptr, nullptr, oh, ol, Hs, logW, dil, 0);
  };
  auto upsC = [&](const unsigned short* ih, const unsigned short* il, long wo,
                  int Hs, int logW, int ccol) {
    ups_mfma_kernel<4><<<dim3(256, 1, 2), 256, 0, stream>>>(
        ih, il, packs + wo, concat, Hs, logW, ccol);
  };
  auto avgp = [&](const unsigned short* ih, const unsigned short* il,
                  unsigned short* oh, unsigned short* ol, int logWo) {
    long total = 2l * (1l << (2 * logWo)) * 8;
    avgpool_nhwc_kernel<<<(int)(total / 256), 256, 0, stream>>>(ih, il, oh, ol, logWo);
  };

  // ---- @256: outs[0], resblock cl10[0], outs[1], resblock cl2[0]
  donutC(Xhi, Xlo, OFF_FIRST, 1, 0);
  conv9(Xhi, Xlo, off_cl10(0), Yhi, Ylo, 256, 8);
  conv9r(Yhi, Ylo, off_cl10(1), Xhi, Xlo, 256, 8);           // base = X @256
  donutC(Xhi, Xlo, off_dilres(0), 3, 64);
  conv9(Xhi, Xlo, off_cl2(0), Yhi, Ylo, 256, 8);
  conv9r(Yhi, Ylo, off_cl2(1), Xhi, Xlo, 256, 8);            // base = X @256

  // ---- i = 0 (dil 5 @256)
  donutA(Xhi, Xlo, off_dil(0), 5, Yhi, Ylo, 256, 8);
  upsC(Yhi, Ylo, off_ups(0), 256, 8, 128);
  avgp(Xhi, Xlo, Yhi, Ylo, 7);                               // base = Y @128
  conv9(Yhi, Ylo, off_cl10(2), Xhi, Xlo, 128, 7);
  conv9r(Xhi, Xlo, off_cl10(3), Yhi, Ylo, 128, 7);           // base = Y @128
  donutA(Yhi, Ylo, off_dilres(1), 6, Xhi, Xlo, 128, 7);
  upsC(Xhi, Xlo, off_ups(1), 128, 7, 192);
  conv9(Yhi, Ylo, off_cl2(2), Xhi, Xlo, 128, 7);
  conv9r(Xhi, Xlo, off_cl2(3), Yhi, Ylo, 128, 7);            // base = Y @128

  // ---- i = 1 (dil 8 @128)
  donutA(Yhi, Ylo, off_dil(1), 8, Xhi, Xlo, 128, 7);
  upsC(Xhi, Xlo, off_ups(1), 128, 7, 256);
  avgp(Yhi, Ylo, Xhi, Xlo, 6);                               // base = X @64
  conv9(Xhi, Xlo, off_cl10(4), Yhi, Ylo, 64, 6);
  conv9r(Yhi, Ylo, off_cl10(5), Xhi, Xlo, 64, 6);            // base = X @64
  donutA(Xhi, Xlo, off_dilres(2), 8, Yhi, Ylo, 64, 6);
  upsC(Yhi, Ylo, off_ups(2), 64, 6, 320);
  conv9(Xhi, Xlo, off_cl2(4), Yhi, Ylo, 64, 6);
  conv9r(Yhi, Ylo, off_cl2(5), Xhi, Xlo, 64, 6);             // base = X @64

  // ---- i = 2 (dil 10 @64)
  donutA(Xhi, Xlo, off_dil(2), 10, Yhi, Ylo, 64, 6);
  upsC(Yhi, Ylo, off_ups(2), 64, 6, 384);
  avgp(Xhi, Xlo, Yhi, Ylo, 5);                               // base = Y @32
  conv9(Yhi, Ylo, off_cl10(6), Xhi, Xlo, 32, 5);
  conv9r(Xhi, Xlo, off_cl10(7), Yhi, Ylo, 32, 5);            // base = Y @32
  donutA(Yhi, Ylo, off_dilres(3), 9, Xhi, Xlo, 32, 5);
  upsC(Xhi, Xlo, off_ups(3), 32, 5, 448);
  conv9(Yhi, Ylo, off_cl2(6), Xhi, Xlo, 32, 5);
  conv9r(Xhi, Xlo, off_cl2(7), Yhi, Ylo, 32, 5);             // base = Y @32

  // ---- i = 3 (dil 11 @32)
  donutA(Yhi, Ylo, off_dil(3), 11, Xhi, Xlo, 32, 5);
  upsC(Xhi, Xlo, off_ups(3), 32, 5, 512);

  // ---- head: 2 px-chunks, h bounced through dead act region
  for (int c = 0; c < 2; c++) {
    out1_gemm_kernel<<<dim3(CHPX / 64, 2), 256, 0, stream>>>(
        concat, w1p, hbuf, c * CHPX);
    out2_gemm_kernel<<<dim3(CHPX / 256, 2), 256, 0, stream>>>(
        hbuf, w2p, w3, (float*)d_out, c * CHPX);
  }
}

// Round 18
// 954.549 us; speedup vs baseline: 1.0782x; 1.0107x over previous
//
#include <hip/hip_runtime.h>
#include <hip/hip_bf16.h>

// ---------------------------------------------------------------------------
// SHINE forward, full bf16-MFMA version with hi/lo-split activations+weights.
// Workspace (222,445,568 B total, unchanged layout):
//   concat : bf16 NHWC [2][65536][576]          150,994,944 B
//   Xhi,Xlo,Yhi,Ylo : bf16 NHWC [2][65536][64]  4 x 16,777,216 B
//   packs  : conv B-frags (hi,lo)                 3,604,480 B
//   w1p    : head W1 frags                          663,552 B
//   w2p    : head W2 frags                           73,728 B
// R18: out1_gemm v6 = NO weight staging (Common Mistake #7: mt-split waves
//      read DIFFERENT frags, so the LDS stage shared nothing and cost 2
//      barriers/kt). B-frags read directly from L2-resident w1p; ZERO
//      barriers in main loop; TLP (4 waves/SIMD) hides latency. LDS kept
//      only for the epilogue transpose. Bit-identical math.
// ---------------------------------------------------------------------------

#define HPX 65536   // 256*256
#define FCH 64
#define CHPX 32768  // head px-chunk

typedef __attribute__((ext_vector_type(8))) short  short8;
typedef __attribute__((ext_vector_type(4))) float  floatx4;

__device__ __forceinline__ float gelu_f(float x) {
  return 0.5f * x * (1.0f + erff(x * 0.70710678118654752440f));
}
__device__ __forceinline__ unsigned short f2bf(float x) {  // RNE
  unsigned u = __float_as_uint(x);
  unsigned r = (u + 0x7FFFu + ((u >> 16) & 1u)) >> 16;
  return (unsigned short)r;
}
__device__ __forceinline__ float bf2f(unsigned short h) {
  return __uint_as_float(((unsigned)h) << 16);
}

// ---------------- conv0 part A: channels 0..47 = gelu(w0b[c] * target)
__global__ __launch_bounds__(256) void conv0_elem_kernel(
    const float* __restrict__ img,   // [2][5][256][256]
    const float* __restrict__ w0b,   // [48]
    unsigned short* __restrict__ ohi,  // [2][65536][64]
    unsigned short* __restrict__ olo)
{
  int t = blockIdx.x * 256 + threadIdx.x;     // over 2*HPX*6 = 786432
  int cg = t % 6;
  int pn = t / 6;                              // n*HPX + px
  int px = pn & (HPX - 1);
  int n  = pn >> 16;
  float x = img[(long)n * 5 * HPX + 2 * HPX + px];
  short8 oh, ol;
  #pragma unroll
  for (int j = 0; j < 8; j++) {
    int c = cg * 8 + j;
    float v = gelu_f(w0b[c] * x);
    unsigned short hb = f2bf(v);
    oh[j] = (short)hb;
    ol[j] = (short)f2bf(v - bf2f(hb));
  }
  long o = ((long)pn) * 64 + cg * 8;
  *(short8*)&ohi[o] = oh;
  *(short8*)&olo[o] = ol;
}

// ---------------- conv0 part B: channels 48..63 = gelu(3x3 conv over 4 feats)
__global__ __launch_bounds__(256) void conv0_conv_kernel(
    const float* __restrict__ img,   // [2][5][256][256]
    const float* __restrict__ w0a,   // [16][4][3][3]
    unsigned short* __restrict__ ohi,
    unsigned short* __restrict__ olo)
{
  int t = blockIdx.x * 256 + threadIdx.x;     // over 2*HPX*2 = 262144
  int cg = t & 1;
  int pn = t >> 1;
  int px = pn & (HPX - 1);
  int n  = pn >> 16;
  int y = px >> 8, x = px & 255;
  const float* im = img + (long)n * 5 * HPX;
  const int map4[4] = {0, 1, 3, 4};
  float vreg[36];
  #pragma unroll
  for (int fi = 0; fi < 4; fi++)
    #pragma unroll
    for (int ky = 0; ky < 3; ky++)
      #pragma unroll
      for (int kx = 0; kx < 3; kx++) {
        int yy = y + ky - 1, xx = x + kx - 1;
        bool ok = ((unsigned)yy < 256u) && ((unsigned)xx < 256u);
        vreg[(fi * 3 + ky) * 3 + kx] =
            ok ? im[(long)map4[fi] * HPX + yy * 256 + xx] : 0.0f;
      }
  short8 oh, ol;
  #pragma unroll
  for (int j = 0; j < 8; j++) {
    int co = cg * 8 + j;                       // 0..15 -> output ch 48+co
    const float* wr = w0a + co * 36;
    float r = 0.0f;
    #pragma unroll
    for (int q = 0; q < 36; q++) r = fmaf(wr[q], vreg[q], r);
    float v = gelu_f(r);
    unsigned short hb = f2bf(v);
    oh[j] = (short)hb;
    ol[j] = (short)f2bf(v - bf2f(hb));
  }
  long o = ((long)pn) * 64 + 48 + cg * 8;
  *(short8*)&ohi[o] = oh;
  *(short8*)&olo[o] = ol;
}

// ---------------- batched conv-weight packing into MFMA B-frags (hi,lo)
struct JobArr { int4 j[29]; };   // {src_sel, src_off, ntaps, dst_off}

__global__ __launch_bounds__(256) void pack_conv_kernel(
    const float* __restrict__ cl10, const float* __restrict__ cl2,
    const float* __restrict__ first_p, const float* __restrict__ dilres_p,
    const float* __restrict__ dil_p, const float* __restrict__ ups_w,
    unsigned short* __restrict__ packs, JobArr jobs)
{
  int4 jb = jobs.j[blockIdx.y];
  int ntaps = jb.z;
  int idx = blockIdx.x * 256 + threadIdx.x;
  if (idx >= ntaps * 8192) return;
  int j  = idx & 7;
  int l  = (idx >> 3) & 63;
  int s  = (idx >> 9) & 1;
  int nt = (idx >> 10) & 3;
  int kt = (idx >> 12) & 1;
  int tap = idx >> 13;
  int oc = nt * 16 + (l & 15);
  int ci = kt * 32 + (l >> 4) * 8 + j;
  const float* src;
  switch (jb.x) {
    case 0: src = cl10; break;
    case 1: src = cl2; break;
    case 2: src = first_p; break;
    case 3: src = dilres_p; break;
    case 4: src = dil_p; break;
    default: src = ups_w; break;
  }
  float w = src[jb.y + (oc * 64 + ci) * ntaps + tap];
  unsigned short hi = f2bf(w);
  unsigned short v = (s == 0) ? hi : f2bf(w - bf2f(hi));
  packs[jb.w + idx] = v;
}

// ---------------- head weight packing (hi+lo)
__global__ __launch_bounds__(256) void pack_w1_kernel(
    const float* __restrict__ w1, unsigned short* __restrict__ w1p)
{
  int t = blockIdx.x * 256 + threadIdx.x;      // 18*18*512
  if (t >= 18 * 18 * 512) return;
  int j = t & 7, l = (t >> 3) & 63;
  int mt = (t >> 9) % 18, kt = (t >> 9) / 18;
  int oc = mt * 16 + (l & 15);
  int k  = kt * 32 + (l >> 4) * 8 + j;
  float w = w1[oc * 576 + k];
  unsigned short hi = f2bf(w);
  unsigned short lo = f2bf(w - bf2f(hi));
  long base = ((long)(kt * 18 + mt) * 2) * 512 + l * 8 + j;
  w1p[base] = hi;
  w1p[base + 512] = lo;
}
__global__ __launch_bounds__(256) void pack_w2_kernel(
    const float* __restrict__ w2, unsigned short* __restrict__ w2p)
{
  int t = blockIdx.x * 256 + threadIdx.x;      // 9*4*512
  if (t >= 9 * 4 * 512) return;
  int j = t & 7, l = (t >> 3) & 63;
  int ot = (t >> 9) % 4, kt = (t >> 9) / 4;
  int oc = ot * 16 + (l & 15);
  int k  = kt * 32 + (l >> 4) * 8 + j;
  float w = w2[oc * 288 + k];
  unsigned short hi = f2bf(w);
  unsigned short lo = f2bf(w - bf2f(hi));
  long base = ((long)(kt * 4 + ot) * 2) * 512 + l * 8 + j;
  w2p[base] = hi;
  w2p[base + 512] = lo;
}

// ---------------- software-pipelined MFMA conv (implicit GEMM, 16x16x32 bf16)
// NOTE: conv_pipe keeps its LDS weight stage — here all 4 waves read the SAME
// tap frags, so the stage legitimately cuts L1/L2 traffic 4x.
template <int NTAPS, int MT, bool RESID, bool TO_CONCAT>
__global__ __launch_bounds__(256) void conv_pipe_kernel(
    const unsigned short* __restrict__ in_hi,   // NHWC [n][npx_in][64]
    const unsigned short* __restrict__ in_lo,
    const unsigned short* __restrict__ wp,      // packed frags
    const unsigned short* __restrict__ res_hi,
    const unsigned short* __restrict__ res_lo,
    unsigned short* __restrict__ out_hi,        // act hi or concat
    unsigned short* __restrict__ out_lo,
    int Hs, int logW, int dil, int ccol)
{
  __shared__ short8 wst[2][1024];               // 2 x 16 KB double buffer
  __shared__ float  ftb[4][16][65];             // per-wave f32 transpose tiles
  const int tid  = threadIdx.x;
  const int lane = tid & 63;
  const int wave = tid >> 6;
  const int row  = lane & 15;
  const int g    = lane >> 4;
  const int n    = blockIdx.z;
  const int Ws   = 1 << logW;
  const int npx_in = Hs << logW;
  const int opx0 = blockIdx.x * (64 * MT) + wave * (16 * MT);

  const unsigned short* ihi = in_hi + (long)n * npx_in * 64;
  const unsigned short* ilo = in_lo + (long)n * npx_in * 64;
  const short8* wpv = (const short8*)wp;

  int ry[MT], rx[MT];
  #pragma unroll
  for (int mt = 0; mt < MT; mt++) {
    int p = opx0 + mt * 16 + row;
    ry[mt] = p >> logW;
    rx[mt] = p & (Ws - 1);
  }

  floatx4 acc[MT][4];
  #pragma unroll
  for (int mt = 0; mt < MT; mt++)
    #pragma unroll
    for (int nt = 0; nt < 4; nt++) acc[mt][nt] = (floatx4){0.f, 0.f, 0.f, 0.f};

  const short8 zz = {0, 0, 0, 0, 0, 0, 0, 0};
  short8 sreg[4];
  short8 ahA[MT][2], alA[MT][2], ahB[MT][2], alB[MT][2];

  auto stage_issue = [&](int t) {
    #pragma unroll
    for (int p = 0; p < 4; p++)
      sreg[p] = wpv[(long)t * 1024 + tid + p * 256];
  };
  auto stage_write = [&](int b) {
    #pragma unroll
    for (int p = 0; p < 4; p++)
      wst[b][tid + p * 256] = sreg[p];
  };
  auto a_load = [&](short8 (&ah)[MT][2], short8 (&al)[MT][2], int t) {
    const int kk  = (NTAPS == 9) ? t : (t < 4 ? t : t + 1);
    const int dyd = (kk / 3 - 1) * dil, dxd = (kk % 3 - 1) * dil;
    #pragma unroll
    for (int mt = 0; mt < MT; mt++) {
      int yy = ry[mt] + dyd, xx = rx[mt] + dxd;
      bool ok = ((unsigned)yy < (unsigned)Hs) && ((unsigned)xx < (unsigned)Ws);
      long base = ok ? (long)((yy << logW) + xx) * 64 : 0;
      #pragma unroll
      for (int kt = 0; kt < 2; kt++) {
        long a = base + kt * 32 + g * 8;
        short8 h = *(const short8*)(ihi + a);
        short8 l = *(const short8*)(ilo + a);
        ah[mt][kt] = ok ? h : zz;
        al[mt][kt] = ok ? l : zz;
      }
    }
  };
  auto compute = [&](int b, short8 (&ah)[MT][2], short8 (&al)[MT][2]) {
    #pragma unroll
    for (int kt = 0; kt < 2; kt++)
      #pragma unroll
      for (int nt = 0; nt < 4; nt++) {
        short8 bh = wst[b][(kt * 4 + nt) * 128 + lane];
        short8 bl = wst[b][(kt * 4 + nt) * 128 + 64 + lane];
        #pragma unroll
        for (int mt = 0; mt < MT; mt++) {
          acc[mt][nt] = __builtin_amdgcn_mfma_f32_16x16x32_bf16(ah[mt][kt], bh, acc[mt][nt], 0, 0, 0);
          acc[mt][nt] = __builtin_amdgcn_mfma_f32_16x16x32_bf16(ah[mt][kt], bl, acc[mt][nt], 0, 0, 0);
          acc[mt][nt] = __builtin_amdgcn_mfma_f32_16x16x32_bf16(al[mt][kt], bh, acc[mt][nt], 0, 0, 0);
        }
      }
  };

  // prologue: stage + A for tap 0
  stage_issue(0);
  a_load(ahA, alA, 0);
  stage_write(0);
  __syncthreads();

  #pragma unroll
  for (int tt = 0; tt < NTAPS; tt++) {
    const int b = tt & 1;
    if (tt + 1 < NTAPS) {
      stage_issue(tt + 1);                       // global loads, early
      if ((tt & 1) == 0) a_load(ahB, alB, tt + 1);
      else               a_load(ahA, alA, tt + 1);
    }
    if ((tt & 1) == 0) compute(b, ahA, alA);     // hides the loads above
    else               compute(b, ahB, alB);
    if (tt + 1 < NTAPS) {
      stage_write(b ^ 1);                        // write-late into other buf
      __syncthreads();                           // ONE barrier per tap
    }
  }

  // epilogue: acc -> f32 LDS tile -> (+coalesced resid) -> gelu -> short8 out
  #pragma unroll
  for (int mt = 0; mt < MT; mt++) {
    __builtin_amdgcn_wave_barrier();
    #pragma unroll
    for (int nt = 0; nt < 4; nt++)
      #pragma unroll
      for (int r = 0; r < 4; r++)
        ftb[wave][g * 4 + r][nt * 16 + row] = acc[mt][nt][r];
    __builtin_amdgcn_wave_barrier();
    const int pxb = opx0 + mt * 16;
    const int pxl = lane >> 2;
    #pragma unroll
    for (int it = 0; it < 2; it++) {
      const int ch = (lane & 3) + it * 4;
      float vv[8];
      #pragma unroll
      for (int j = 0; j < 8; j++) vv[j] = ftb[wave][pxl][ch * 8 + j];
      if (RESID) {
        long rb = ((long)n * npx_in + pxb + pxl) * 64 + ch * 8;
        short8 rh = *(const short8*)(res_hi + rb);
        short8 rl = *(const short8*)(res_lo + rb);
        #pragma unroll
        for (int j = 0; j < 8; j++)
          vv[j] += bf2f((unsigned short)rh[j]) + bf2f((unsigned short)rl[j]);
      }
      short8 oh8, ol8;
      #pragma unroll
      for (int j = 0; j < 8; j++) {
        float v = gelu_f(vv[j]);
        unsigned short hb = f2bf(v);
        oh8[j] = (short)hb;
        ol8[j] = (short)f2bf(v - bf2f(hb));
      }
      if (TO_CONCAT) {
        *(short8*)&out_hi[((long)n * HPX + pxb + pxl) * 576 + ccol + ch * 8] = oh8;
      } else {
        *(short8*)&out_hi[((long)n * npx_in + pxb + pxl) * 64 + ch * 8] = oh8;
        *(short8*)&out_lo[((long)n * npx_in + pxb + pxl) * 64 + ch * 8] = ol8;
      }
    }
  }
}

// ---------------- bilinear-upsample 1x1 conv -> concat (coalesced epilogue)
template <int MT>
__global__ __launch_bounds__(256) void ups_mfma_kernel(
    const unsigned short* __restrict__ in_hi,   // NHWC [n][npx_in][64]
    const unsigned short* __restrict__ in_lo,
    const unsigned short* __restrict__ wp,      // packed frags (1 tap)
    unsigned short* __restrict__ outc,          // concat
    int Hs, int logW, int ccol)
{
  __shared__ short8 wst[1024];                  // 16 KB: one tap's 16 frags
  __shared__ unsigned short tb[4][16][76];
  const int tid  = threadIdx.x;
  const int lane = threadIdx.x & 63;
  const int wave = threadIdx.x >> 6;
  const int row  = lane & 15;
  const int g    = lane >> 4;
  const int n    = blockIdx.z;
  const int npx_in = Hs << logW;
  const int opx0 = blockIdx.x * (64 * MT) + wave * (16 * MT);

  const unsigned short* ihi = in_hi + (long)n * npx_in * 64;
  const unsigned short* ilo = in_lo + (long)n * npx_in * 64;
  const short8* wpv = (const short8*)wp;

  int b00[MT], b01[MT], b10[MT], b11[MT];
  float bwx[MT], bwy[MT];
  #pragma unroll
  for (int mt = 0; mt < MT; mt++) {
    int p = opx0 + mt * 16 + row;
    int Y = p >> 8, X = p & 255;
    float sc = (float)Hs * (1.0f / 256.0f);
    float fy = ((float)Y + 0.5f) * sc - 0.5f;
    float fx = ((float)X + 0.5f) * sc - 0.5f;
    int y0 = (int)floorf(fy), x0 = (int)floorf(fx);
    bwy[mt] = fy - (float)y0; bwx[mt] = fx - (float)x0;
    int y0c = min(max(y0, 0), Hs - 1), y1c = min(max(y0 + 1, 0), Hs - 1);
    int x0c = min(max(x0, 0), Hs - 1), x1c = min(max(x0 + 1, 0), Hs - 1);
    b00[mt] = (y0c * Hs + x0c) * 64; b01[mt] = (y0c * Hs + x1c) * 64;
    b10[mt] = (y1c * Hs + x0c) * 64; b11[mt] = (y1c * Hs + x1c) * 64;
  }

  floatx4 acc[MT][4];
  #pragma unroll
  for (int mt = 0; mt < MT; mt++)
    #pragma unroll
    for (int nt = 0; nt < 4; nt++) acc[mt][nt] = (floatx4){0.f, 0.f, 0.f, 0.f};

  #pragma unroll
  for (int p = 0; p < 4; p++)
    wst[tid + p * 256] = wpv[tid + p * 256];
  __syncthreads();

  #pragma unroll
  for (int kt = 0; kt < 2; kt++) {
    const int ko = kt * 32 + g * 8;
    short8 ah[MT], al[MT];
    #pragma unroll
    for (int mt = 0; mt < MT; mt++) {
      short8 h00 = *(const short8*)(ihi + b00[mt] + ko);
      short8 l00 = *(const short8*)(ilo + b00[mt] + ko);
      short8 h01 = *(const short8*)(ihi + b01[mt] + ko);
      short8 l01 = *(const short8*)(ilo + b01[mt] + ko);
      short8 h10 = *(const short8*)(ihi + b10[mt] + ko);
      short8 l10 = *(const short8*)(ilo + b10[mt] + ko);
      short8 h11 = *(const short8*)(ihi + b11[mt] + ko);
      short8 l11 = *(const short8*)(ilo + b11[mt] + ko);
      short8 hh, ll;
      #pragma unroll
      for (int j = 0; j < 8; j++) {
        float v00 = bf2f((unsigned short)h00[j]) + bf2f((unsigned short)l00[j]);
        float v01 = bf2f((unsigned short)h01[j]) + bf2f((unsigned short)l01[j]);
        float v10 = bf2f((unsigned short)h10[j]) + bf2f((unsigned short)l10[j]);
        float v11 = bf2f((unsigned short)h11[j]) + bf2f((unsigned short)l11[j]);
        float v0 = v00 + bwx[mt] * (v01 - v00);
        float v1 = v10 + bwx[mt] * (v11 - v10);
        float v  = v0 + bwy[mt] * (v1 - v0);
        unsigned short hb = f2bf(v);
        hh[j] = (short)hb;
        ll[j] = (short)f2bf(v - bf2f(hb));
      }
      ah[mt] = hh; al[mt] = ll;
    }
    #pragma unroll
    for (int nt = 0; nt < 4; nt++) {
      short8 bh = wst[(kt * 4 + nt) * 2 * 64 + lane];
      short8 bl = wst[((kt * 4 + nt) * 2 + 1) * 64 + lane];
      #pragma unroll
      for (int mt = 0; mt < MT; mt++) {
        acc[mt][nt] = __builtin_amdgcn_mfma_f32_16x16x32_bf16(ah[mt], bh, acc[mt][nt], 0, 0, 0);
        acc[mt][nt] = __builtin_amdgcn_mfma_f32_16x16x32_bf16(ah[mt], bl, acc[mt][nt], 0, 0, 0);
        acc[mt][nt] = __builtin_amdgcn_mfma_f32_16x16x32_bf16(al[mt], bh, acc[mt][nt], 0, 0, 0);
      }
    }
  }

  #pragma unroll
  for (int mt = 0; mt < MT; mt++) {
    __builtin_amdgcn_wave_barrier();
    #pragma unroll
    for (int nt = 0; nt < 4; nt++)
      #pragma unroll
      for (int r = 0; r < 4; r++)
        tb[wave][g * 4 + r][nt * 16 + row] = f2bf(gelu_f(acc[mt][nt][r]));
    __builtin_amdgcn_wave_barrier();
    const int pxb = opx0 + mt * 16;
    const int pxl = lane >> 2;
    #pragma unroll
    for (int it = 0; it < 2; it++) {
      int ch = (lane & 3) + it * 4;
      short8 v8 = *(const short8*)&tb[wave][pxl][ch * 8];
      *(short8*)&outc[((long)n * HPX + pxb + pxl) * 576 + ccol + ch * 8] = v8;
    }
  }
}

// ---------------- 2x2 average pool, NHWC hi/lo -> NHWC hi/lo
__global__ __launch_bounds__(256) void avgpool_nhwc_kernel(
    const unsigned short* __restrict__ ihi, const unsigned short* __restrict__ ilo,
    unsigned short* __restrict__ ohi, unsigned short* __restrict__ olo,
    int logWo)
{
  const int lognpo = 2 * logWo;
  long t = (long)blockIdx.x * 256 + threadIdx.x;   // over 2*npo*8
  int cg = (int)(t & 7);
  int p  = (int)((t >> 3) & ((1 << lognpo) - 1));
  int n  = (int)(t >> (3 + lognpo));
  int y = p >> logWo, x = p & ((1 << logWo) - 1);
  int Wi = 2 << logWo;
  long ib = ((long)n * (4 << lognpo) + (long)(2 * y) * Wi + 2 * x) * 64 + cg * 8;
  short8 h00 = *(const short8*)(ihi + ib);
  short8 h01 = *(const short8*)(ihi + ib + 64);
  short8 h10 = *(const short8*)(ihi + ib + (long)Wi * 64);
  short8 h11 = *(const short8*)(ihi + ib + (long)Wi * 64 + 64);
  short8 l00 = *(const short8*)(ilo + ib);
  short8 l01 = *(const short8*)(ilo + ib + 64);
  short8 l10 = *(const short8*)(ilo + ib + (long)Wi * 64);
  short8 l11 = *(const short8*)(ilo + ib + (long)Wi * 64 + 64);
  short8 oh, ol;
  #pragma unroll
  for (int j = 0; j < 8; j++) {
    float v = 0.25f * ((bf2f((unsigned short)h00[j]) + bf2f((unsigned short)l00[j])) +
                       (bf2f((unsigned short)h01[j]) + bf2f((unsigned short)l01[j])) +
                       (bf2f((unsigned short)h10[j]) + bf2f((unsigned short)l10[j])) +
                       (bf2f((unsigned short)h11[j]) + bf2f((unsigned short)l11[j])));
    unsigned short hb = f2bf(v);
    oh[j] = (short)hb;
    ol[j] = (short)f2bf(v - bf2f(hb));
  }
  long ob = (((long)n << lognpo) + p) * 64 + cg * 8;
  *(short8*)(ohi + ob) = oh;
  *(short8*)(olo + ob) = ol;
}

// ---------------- head stage 1 GEMM v6: h = gelu(W1 @ concat), one px-chunk
// 64 px/block, 4 waves mt-split {5,5,4,4}. NO weight staging: each wave reads
// its own B-frags straight from L2-resident w1p (1KB contiguous, coalesced).
// ZERO barriers in the main loop -> waves run free, TLP hides latency.
// LDS used only for the epilogue stride-300 transpose. Math order identical.
__global__ __launch_bounds__(256) void out1_gemm_kernel(
    const unsigned short* __restrict__ v,       // concat NHWC [2][65536][576]
    const unsigned short* __restrict__ w1p,
    unsigned short* __restrict__ h,             // [2][CHPX][288] bf16
    int cpx)
{
  __shared__ unsigned short hs2[64 * 300];      // 38,400 B (epilogue only)
  const int tid  = threadIdx.x;
  const int lane = tid & 63;
  const int wave = tid >> 6;
  const int row  = lane & 15;
  const int g    = lane >> 4;
  const int n    = blockIdx.y;
  const int px0  = cpx + blockIdx.x * 64;       // absolute px
  const int mtb  = (wave < 2) ? wave * 5 : 10 + (wave - 2) * 4;
  const int MTN  = (wave < 2) ? 5 : 4;
  const short8* w1v = (const short8*)w1p;
  const unsigned short* vb = v + ((long)n * HPX + px0) * 576;

  floatx4 acc[4][5];
  #pragma unroll
  for (int t = 0; t < 4; t++)
    #pragma unroll
    for (int m = 0; m < 5; m++) acc[t][m] = (floatx4){0.f, 0.f, 0.f, 0.f};

  #pragma unroll 2
  for (int kt = 0; kt < 18; kt++) {
    short8 a[4];
    #pragma unroll
    for (int t = 0; t < 4; t++)
      a[t] = *(const short8*)(vb + (long)(t * 16 + row) * 576 + kt * 32 + g * 8);
    #pragma unroll
    for (int m = 0; m < 5; m++) {
      if (m < MTN) {
        short8 bh = w1v[(long)(kt * 18 + mtb + m) * 128 + lane];
        short8 bl = w1v[(long)(kt * 18 + mtb + m) * 128 + 64 + lane];
        #pragma unroll
        for (int t = 0; t < 4; t++) {
          acc[t][m] = __builtin_amdgcn_mfma_f32_16x16x32_bf16(a[t], bh, acc[t][m], 0, 0, 0);
          acc[t][m] = __builtin_amdgcn_mfma_f32_16x16x32_bf16(a[t], bl, acc[t][m], 0, 0, 0);
        }
      }
    }
  }

  // epilogue: gelu -> bf16 -> LDS [64][300] -> coalesced h writes
  #pragma unroll
  for (int m = 0; m < 5; m++) {
    if (m < MTN) {
      #pragma unroll
      for (int t = 0; t < 4; t++)
        #pragma unroll
        for (int r = 0; r < 4; r++)
          hs2[(t * 16 + g * 4 + r) * 300 + (mtb + m) * 16 + row] =
              f2bf(gelu_f(acc[t][m][r]));
    }
  }
  __syncthreads();
  #pragma unroll
  for (int p = 0; p < 9; p++) {
    int li = tid + p * 256;                      // 2304 chunks of 16B
    int px = li / 36, c16 = li % 36;
    short8 v8 = *(const short8*)&hs2[px * 300 + c16 * 8];
    *(short8*)&h[((long)n * CHPX + (px0 - cpx) + px) * 288 + c16 * 8] = v8;
  }
}

// ---------------- head stage 2: out = w3 . gelu(W2 @ h), one px-chunk
__global__ __launch_bounds__(256) void out2_gemm_kernel(
    const unsigned short* __restrict__ h,       // [2][CHPX][288] bf16
    const unsigned short* __restrict__ w2p,
    const float* __restrict__ w3,               // [64]
    float* __restrict__ out,                    // [2][65536]
    int cpx)
{
  __shared__ short8 w2s[4608];                  // 73,728 B, whole w2p
  const int tid  = threadIdx.x;
  const int lane = tid & 63;
  const int wave = tid >> 6;
  const int row  = lane & 15;
  const int g    = lane >> 4;
  const int n    = blockIdx.y;
  const int pxc  = blockIdx.x * 256 + wave * 64; // px within chunk
  const short8* w2v = (const short8*)w2p;

  #pragma unroll
  for (int p = 0; p < 18; p++)
    w2s[tid + p * 256] = w2v[tid + p * 256];
  __syncthreads();

  floatx4 acc2[4][4];
  #pragma unroll
  for (int t = 0; t < 4; t++)
    #pragma unroll
    for (int ot = 0; ot < 4; ot++) acc2[t][ot] = (floatx4){0.f, 0.f, 0.f, 0.f};

  for (int kt = 0; kt < 9; kt++) {
    short8 a[4];
    #pragma unroll
    for (int t = 0; t < 4; t++)
      a[t] = *(const short8*)&h[((long)n * CHPX + pxc + t * 16 + row) * 288 +
                                kt * 32 + g * 8];
    #pragma unroll
    for (int ot = 0; ot < 4; ot++) {
      short8 bh = w2s[((kt * 4 + ot) * 2 + 0) * 64 + lane];
      short8 bl = w2s[((kt * 4 + ot) * 2 + 1) * 64 + lane];
      #pragma unroll
      for (int t = 0; t < 4; t++) {
        acc2[t][ot] = __builtin_amdgcn_mfma_f32_16x16x32_bf16(a[t], bh, acc2[t][ot], 0, 0, 0);
        acc2[t][ot] = __builtin_amdgcn_mfma_f32_16x16x32_bf16(a[t], bl, acc2[t][ot], 0, 0, 0);
      }
    }
  }

  float w3r[4];
  #pragma unroll
  for (int ot = 0; ot < 4; ot++) w3r[ot] = w3[ot * 16 + row];
  #pragma unroll
  for (int t = 0; t < 4; t++) {
    float r[4] = {0.f, 0.f, 0.f, 0.f};
    #pragma unroll
    for (int ot = 0; ot < 4; ot++)
      #pragma unroll
      for (int rr = 0; rr < 4; rr++)
        r[rr] = fmaf(w3r[ot], gelu_f(acc2[t][ot][rr]), r[rr]);
    #pragma unroll
    for (int rr = 0; rr < 4; rr++) {
      r[rr] += __shfl_xor(r[rr], 1);
      r[rr] += __shfl_xor(r[rr], 2);
      r[rr] += __shfl_xor(r[rr], 4);
      r[rr] += __shfl_xor(r[rr], 8);
    }
    if (row == 0) {
      int px = cpx + pxc + t * 16 + g * 4;
      #pragma unroll
      for (int rr = 0; rr < 4; rr++)
        out[(long)n * HPX + px + rr] = r[rr];
    }
  }
}

// ---------------------------------------------------------------------------
extern "C" void kernel_launch(void* const* d_in, const int* in_sizes, int n_in,
                              void* d_out, int out_size, void* d_ws, size_t ws_size,
                              hipStream_t stream) {
  const float* img      = (const float*)d_in[0];
  const float* w0a      = (const float*)d_in[1];
  const float* w0b      = (const float*)d_in[2];
  const float* first_p  = (const float*)d_in[3];
  const float* cl10     = (const float*)d_in[4];   // [4][2][64][64][9]
  const float* cl2      = (const float*)d_in[5];
  const float* dil_p    = (const float*)d_in[6];   // [4][64][64][8]
  const float* dilres_p = (const float*)d_in[7];
  const float* ups_w    = (const float*)d_in[8];   // [4][64][64]
  const float* w1       = (const float*)d_in[9];   // [288][576]
  const float* w2       = (const float*)d_in[10];  // [64][288]
  const float* w3       = (const float*)d_in[11];  // [64]

  const size_t CONCAT_B = 150994944ul;             // 2*65536*576*2
  const size_t ACT_B    = 16777216ul;              // 2*65536*64*2 per plane
  const size_t PACKS_B  = 3604480ul;               // 1,802,240 elems
  const size_t W1P_B    = 663552ul;
  const size_t W2P_B    = 73728ul;
  const size_t NEED = CONCAT_B + 4 * ACT_B + PACKS_B + W1P_B + W2P_B; // 222,445,568

  if (ws_size < NEED) {
    hipMemsetAsync(d_out, 0, (size_t)out_size * 4, stream);
    return;
  }

  char* wsb = (char*)d_ws;
  unsigned short* concat = (unsigned short*)wsb;
  unsigned short* Xhi = (unsigned short*)(wsb + CONCAT_B);
  unsigned short* Xlo = (unsigned short*)(wsb + CONCAT_B + ACT_B);
  unsigned short* Yhi = (unsigned short*)(wsb + CONCAT_B + 2 * ACT_B);
  unsigned short* Ylo = (unsigned short*)(wsb + CONCAT_B + 3 * ACT_B);
  unsigned short* packs = (unsigned short*)(wsb + CONCAT_B + 4 * ACT_B);
  unsigned short* w1p = (unsigned short*)(wsb + CONCAT_B + 4 * ACT_B + PACKS_B);
  unsigned short* w2p = (unsigned short*)(wsb + CONCAT_B + 4 * ACT_B + PACKS_B + W1P_B);
  unsigned short* hbuf = Xhi;   // head h buffer reuses dead act region

  // pack-destination offsets (elems)
  auto off_cl10   = [](int c) { return (long)c * 73728; };
  auto off_cl2    = [](int c) { return 589824l + (long)c * 73728; };
  const long OFF_FIRST = 1179648;
  auto off_dilres = [](int k) { return 1245184l + (long)k * 65536; };
  auto off_dil    = [](int k) { return 1507328l + (long)k * 65536; };
  auto off_ups    = [](int k) { return 1769472l + (long)k * 8192; };

  // ---- weight packing
  JobArr jobs;
  for (int c = 0; c < 8; c++) jobs.j[c]     = {0, c * 36864, 9, (int)off_cl10(c)};
  for (int c = 0; c < 8; c++) jobs.j[8 + c] = {1, c * 36864, 9, (int)off_cl2(c)};
  jobs.j[16] = {2, 0, 8, (int)OFF_FIRST};
  for (int k = 0; k < 4; k++) jobs.j[17 + k] = {3, k * 32768, 8, (int)off_dilres(k)};
  for (int k = 0; k < 4; k++) jobs.j[21 + k] = {4, k * 32768, 8, (int)off_dil(k)};
  for (int k = 0; k < 4; k++) jobs.j[25 + k] = {5, k * 4096, 1, (int)off_ups(k)};
  pack_conv_kernel<<<dim3(288, 29), 256, 0, stream>>>(
      cl10, cl2, first_p, dilres_p, dil_p, ups_w, packs, jobs);
  pack_w1_kernel<<<(18 * 18 * 512 + 255) / 256, 256, 0, stream>>>(w1, w1p);
  pack_w2_kernel<<<(9 * 4 * 512 + 255) / 256, 256, 0, stream>>>(w2, w2p);

  // ---- conv0 -> X @256 (elementwise part + 3x3 part)
  conv0_elem_kernel<<<(2 * HPX * 6) / 256, 256, 0, stream>>>(img, w0b, Xhi, Xlo);
  conv0_conv_kernel<<<(2 * HPX * 2) / 256, 256, 0, stream>>>(img, w0a, Xhi, Xlo);

  // ---- launch helpers (pipelined convs; MT=2 @256, MT=1 below)
  auto conv9 = [&](const unsigned short* ih, const unsigned short* il, long wo,
                   unsigned short* oh, unsigned short* ol, int Hs, int logW) {
    int npx = Hs << logW;
    if (npx == HPX)
      conv_pipe_kernel<9, 2, false, false><<<dim3(npx / 128, 1, 2), 256, 0, stream>>>(
          ih, il, packs + wo, nullptr, nullptr, oh, ol, Hs, logW, 1, 0);
    else
      conv_pipe_kernel<9, 1, false, false><<<dim3(npx / 64, 1, 2), 256, 0, stream>>>(
          ih, il, packs + wo, nullptr, nullptr, oh, ol, Hs, logW, 1, 0);
  };
  auto conv9r = [&](const unsigned short* ih, const unsigned short* il, long wo,
                    unsigned short* rh, unsigned short* rl, int Hs, int logW) {
    int npx = Hs << logW;
    if (npx == HPX)
      conv_pipe_kernel<9, 2, true, false><<<dim3(npx / 128, 1, 2), 256, 0, stream>>>(
          ih, il, packs + wo, rh, rl, rh, rl, Hs, logW, 1, 0);
    else
      conv_pipe_kernel<9, 1, true, false><<<dim3(npx / 64, 1, 2), 256, 0, stream>>>(
          ih, il, packs + wo, rh, rl, rh, rl, Hs, logW, 1, 0);
  };
  auto donutC = [&](const unsigned short* ih, const unsigned short* il, long wo,
                    int dil, int ccol) {  // @256 -> concat
    conv_pipe_kernel<8, 2, false, true><<<dim3(512, 1, 2), 256, 0, stream>>>(
        ih, il, packs + wo, nullptr, nullptr, concat, nullptr, 256, 8, dil, ccol);
  };
  auto donutA = [&](const unsigned short* ih, const unsigned short* il, long wo,
                    int dil, unsigned short* oh, unsigned short* ol, int Hs, int logW) {
    int npx = Hs << logW;
    if (npx == HPX)
      conv_pipe_kernel<8, 2, false, false><<<dim3(npx / 128, 1, 2), 256, 0, stream>>>(
          ih, il, packs + wo, nullptr, nullptr, oh, ol, Hs, logW, dil, 0);
    else
      conv_pipe_kernel<8, 1, false, false><<<dim3(npx / 64, 1, 2), 256, 0, stream>>>(
          ih, il, packs + wo, nullptr, nullptr, oh, ol, Hs, logW, dil, 0);
  };
  auto upsC = [&](const unsigned short* ih, const unsigned short* il, long wo,
                  int Hs, int logW, int ccol) {
    ups_mfma_kernel<4><<<dim3(256, 1, 2), 256, 0, stream>>>(
        ih, il, packs + wo, concat, Hs, logW, ccol);
  };
  auto avgp = [&](const unsigned short* ih, const unsigned short* il,
                  unsigned short* oh, unsigned short* ol, int logWo) {
    long total = 2l * (1l << (2 * logWo)) * 8;
    avgpool_nhwc_kernel<<<(int)(total / 256), 256, 0, stream>>>(ih, il, oh, ol, logWo);
  };

  // ---- @256: outs[0], resblock cl10[0], outs[1], resblock cl2[0]
  donutC(Xhi, Xlo, OFF_FIRST, 1, 0);
  conv9(Xhi, Xlo, off_cl10(0), Yhi, Ylo, 256, 8);
  conv9r(Yhi, Ylo, off_cl10(1), Xhi, Xlo, 256, 8);           // base = X @256
  donutC(Xhi, Xlo, off_dilres(0), 3, 64);
  conv9(Xhi, Xlo, off_cl2(0), Yhi, Ylo, 256, 8);
  conv9r(Yhi, Ylo, off_cl2(1), Xhi, Xlo, 256, 8);            // base = X @256

  // ---- i = 0 (dil 5 @256)
  donutA(Xhi, Xlo, off_dil(0), 5, Yhi, Ylo, 256, 8);
  upsC(Yhi, Ylo, off_ups(0), 256, 8, 128);
  avgp(Xhi, Xlo, Yhi, Ylo, 7);                               // base = Y @128
  conv9(Yhi, Ylo, off_cl10(2), Xhi, Xlo, 128, 7);
  conv9r(Xhi, Xlo, off_cl10(3), Yhi, Ylo, 128, 7);           // base = Y @128
  donutA(Yhi, Ylo, off_dilres(1), 6, Xhi, Xlo, 128, 7);
  upsC(Xhi, Xlo, off_ups(1), 128, 7, 192);
  conv9(Yhi, Ylo, off_cl2(2), Xhi, Xlo, 128, 7);
  conv9r(Xhi, Xlo, off_cl2(3), Yhi, Ylo, 128, 7);            // base = Y @128

  // ---- i = 1 (dil 8 @128)
  donutA(Yhi, Ylo, off_dil(1), 8, Xhi, Xlo, 128, 7);
  upsC(Xhi, Xlo, off_ups(1), 128, 7, 256);
  avgp(Yhi, Ylo, Xhi, Xlo, 6);                               // base = X @64
  conv9(Xhi, Xlo, off_cl10(4), Yhi, Ylo, 64, 6);
  conv9r(Yhi, Ylo, off_cl10(5), Xhi, Xlo, 64, 6);            // base = X @64
  donutA(Xhi, Xlo, off_dilres(2), 8, Yhi, Ylo, 64, 6);
  upsC(Yhi, Ylo, off_ups(2), 64, 6, 320);
  conv9(Xhi, Xlo, off_cl2(4), Yhi, Ylo, 64, 6);
  conv9r(Yhi, Ylo, off_cl2(5), Xhi, Xlo, 64, 6);             // base = X @64

  // ---- i = 2 (dil 10 @64)
  donutA(Xhi, Xlo, off_dil(2), 10, Yhi, Ylo, 64, 6);
  upsC(Yhi, Ylo, off_ups(2), 64, 6, 384);
  avgp(Xhi, Xlo, Yhi, Ylo, 5);                               // base = Y @32
  conv9(Yhi, Ylo, off_cl10(6), Xhi, Xlo, 32, 5);
  conv9r(Xhi, Xlo, off_cl10(7), Yhi, Ylo, 32, 5);            // base = Y @32
  donutA(Yhi, Ylo, off_dilres(3), 9, Xhi, Xlo, 32, 5);
  upsC(Xhi, Xlo, off_ups(3), 32, 5, 448);
  conv9(Yhi, Ylo, off_cl2(6), Xhi, Xlo, 32, 5);
  conv9r(Xhi, Xlo, off_cl2(7), Yhi, Ylo, 32, 5);             // base = Y @32

  // ---- i = 3 (dil 11 @32)
  donutA(Yhi, Ylo, off_dil(3), 11, Xhi, Xlo, 32, 5);
  upsC(Xhi, Xlo, off_ups(3), 32, 5, 512);

  // ---- head: 2 px-chunks, h bounced through dead act region
  for (int c = 0; c < 2; c++) {
    out1_gemm_kernel<<<dim3(CHPX / 64, 2), 256, 0, stream>>>(
        concat, w1p, hbuf, c * CHPX);
    out2_gemm_kernel<<<dim3(CHPX / 256, 2), 256, 0, stream>>>(
        hbuf, w2p, w3, (float*)d_out, c * CHPX);
  }
}